// Round 17
// baseline (236.672 us; speedup 1.0000x reference)
//
#include <hip/hip_runtime.h>
#include <math.h>

// Problem constants (B=4, T=2048, C=1024, H=16, hs=64)
#define B_   4
#define T_   2048
#define C_   1024
#define H_   16
#define HS   64
#define HALF 32
#define QKV_N (3 * C_)      // 3072
#define M_    (B_ * T_)     // 8192

using bf16x8 = __attribute__((ext_vector_type(8))) short;
using f32x4  = __attribute__((ext_vector_type(4))) float;
using f32x16 = __attribute__((ext_vector_type(16))) float;
using u16x4  = __attribute__((ext_vector_type(4))) unsigned short;
using u32x2  = __attribute__((ext_vector_type(2))) unsigned int;

__device__ __forceinline__ unsigned short f2bf(float f) {
    unsigned u = __builtin_bit_cast(unsigned, f);
    u = (u + 0x7FFFu + ((u >> 16) & 1u)) >> 16;
    return (unsigned short)u;
}
__device__ __forceinline__ float bf2f(unsigned short b) {
    return __builtin_bit_cast(float, (unsigned)b << 16);
}
__device__ __forceinline__ unsigned cvtpk_bf16(float lo, float hi_) {
    unsigned r;
    asm("v_cvt_pk_bf16_f32 %0, %1, %2" : "=v"(r) : "v"(lo), "v"(hi_));
    return r;
}
__device__ __forceinline__ void gload16(const void* g, void* l) {
    __builtin_amdgcn_global_load_lds(
        (const __attribute__((address_space(1))) unsigned int*)g,
        (__attribute__((address_space(3))) unsigned int*)l, 16, 0, 0);
}
#define WAIT_VMCNT_8() asm volatile("s_waitcnt vmcnt(8)" ::: "memory")
#define WAIT_VMCNT_4() asm volatile("s_waitcnt vmcnt(4)" ::: "memory")
#define WAIT_VMCNT_0() asm volatile("s_waitcnt vmcnt(0)" ::: "memory")
#define WAIT_LGKM_0()  asm volatile("s_waitcnt lgkmcnt(0)" ::: "memory")

#if __has_builtin(__builtin_amdgcn_exp2f)
#define EXP2(x) __builtin_amdgcn_exp2f(x)
#else
#define EXP2(x) exp2f(x)
#endif
#define FMAX3(a, b, c) fmaxf(fmaxf((a), (b)), (c))

#define QSCALE 0.18033688011112042f   // 0.125 * log2(e), folded into Q

// ---------------------------------------------------------------------------
// prep2: blocks [0,4096): fp32->bf16 cast of x
//        blocks [4096,4352): RoPE sin/cos table
//        blocks [4352,7424): Wqkv transpose+cast
//        blocks [7424,8448): Wout transpose+cast
// ---------------------------------------------------------------------------
__global__ __launch_bounds__(256) void prep2_kernel(
    const float* __restrict__ x, unsigned short* __restrict__ xb,
    float2* __restrict__ tab,
    const float* __restrict__ Wqkv, const float* __restrict__ Wout,
    unsigned short* __restrict__ Wqkvt, unsigned short* __restrict__ Woutt)
{
    __shared__ float tile[32][33];
    const int bid = blockIdx.x;
    if (bid < 4096) {
        const size_t i = ((size_t)bid * 256 + threadIdx.x) * 8;
        const float4 a = *reinterpret_cast<const float4*>(&x[i]);
        const float4 b = *reinterpret_cast<const float4*>(&x[i + 4]);
        bf16x8 v;
        v[0] = f2bf(a.x); v[1] = f2bf(a.y); v[2] = f2bf(a.z); v[3] = f2bf(a.w);
        v[4] = f2bf(b.x); v[5] = f2bf(b.y); v[6] = f2bf(b.z); v[7] = f2bf(b.w);
        *reinterpret_cast<bf16x8*>(&xb[i]) = v;
        return;
    }
    if (bid < 4352) {
        const int idx = (bid - 4096) * 256 + threadIdx.x;   // 0 .. T_*HALF-1
        const int t = idx / HALF;
        const int i = idx % HALF;
        const float theta = powf(10000.0f, -(float)i / (float)HALF);
        const float ang = (float)t * theta;
        float sn, cs;
        sincosf(ang, &sn, &cs);
        tab[idx] = make_float2(sn, cs);
        return;
    }
    const float* W;
    unsigned short* Wt;
    int N, k0, n0;
    if (bid < 7424) {
        const int r0 = bid - 4352;
        W = Wqkv; Wt = Wqkvt; N = QKV_N;
        n0 = (r0 % 96) * 32; k0 = (r0 / 96) * 32;
    } else {
        const int r0 = bid - 7424;
        W = Wout; Wt = Woutt; N = C_;
        n0 = (r0 % 32) * 32; k0 = (r0 / 32) * 32;
    }
    const int K = C_;
    const int r = threadIdx.x / 32;
    const int c = threadIdx.x % 32;
    #pragma unroll
    for (int it = 0; it < 4; ++it)
        tile[r + it * 8][c] = W[(size_t)(k0 + r + it * 8) * N + n0 + c];
    __syncthreads();
    #pragma unroll
    for (int it = 0; it < 4; ++it)
        Wt[(size_t)(n0 + r + it * 8) * K + k0 + c] = f2bf(tile[c][r + it * 8]);
}

// ---------------------------------------------------------------------------
// 8-phase bf16 MFMA GEMM (R12/R13 version — QKV). BM=BN=256, BK=64,
// 512 threads = 8 waves, per-wave 128x64 (acc[8][4]).
// ---------------------------------------------------------------------------
template <int N, int K, bool BF16OUT, bool ROPE, bool VSPLIT>
__global__ __launch_bounds__(512, 1) void gemm_8ph_kernel(
    const unsigned short* __restrict__ A, const unsigned short* __restrict__ Bt,
    const float* __restrict__ bias, const float2* __restrict__ tab,
    void* __restrict__ Cout, unsigned short* __restrict__ vt, int nbx, int nby)
{
    __shared__ unsigned short As0[2][128 * 64];
    __shared__ unsigned short As1[2][128 * 64];
    __shared__ unsigned short Bs0[2][128 * 64];
    __shared__ unsigned short Bs1[2][128 * 64];

    const int tid  = threadIdx.x;
    const int lane = tid & 63;
    const int wave = tid >> 6;        // 0..7
    const int wr   = wave >> 2;       // 0..1 : M half (128 rows)
    const int wc   = wave & 3;        // 0..3 : N quarter (64 cols)
    const int l15  = lane & 15;
    const int l4   = lane >> 4;

    const int bid  = blockIdx.x;
    const int xcd  = bid & 7;
    const int w    = bid >> 3;
    const int cpr  = nbx >> 1;
    const int rpr  = nby >> 2;
    const int by   = ((xcd >> 1) * rpr) + (w / cpr);
    const int bx   = ((xcd & 1) * cpr) + (w % cpr);
    const int row0 = by * 256;
    const int col0 = bx * 256;

    const int lr0 = tid >> 3,          sl0 = tid & 7;
    const int lr1 = (tid + 512) >> 3,  sl1 = (tid + 512) & 7;
    const int kc0 = (sl0 ^ (lr0 & 7)) * 8;
    const int kc1 = (sl1 ^ (lr1 & 7)) * 8;
    const int dA0 = tid * 8;
    const int dA1 = (tid + 512) * 8;
    const unsigned short* apS0 = &A[(size_t)(row0 + (lr0 >> 6) * 128 + (lr0 & 63)) * K + kc0];
    const unsigned short* apS1 = &A[(size_t)(row0 + (lr1 >> 6) * 128 + (lr1 & 63)) * K + kc1];
    const unsigned short* bpS0 = &Bt[(size_t)(col0 + (lr0 >> 5) * 64 + (lr0 & 31)) * K + kc0];
    const unsigned short* bpS1 = &Bt[(size_t)(col0 + (lr1 >> 5) * 64 + (lr1 & 31)) * K + kc1];

    auto stA0 = [&](int buf, int t) {
        gload16(apS0 + t * 64,            &As0[buf][dA0]);
        gload16(apS1 + t * 64,            &As0[buf][dA1]);
    };
    auto stA1 = [&](int buf, int t) {
        gload16(apS0 + t * 64 + 64 * K,   &As1[buf][dA0]);
        gload16(apS1 + t * 64 + 64 * K,   &As1[buf][dA1]);
    };
    auto stB0 = [&](int buf, int t) {
        gload16(bpS0 + t * 64,            &Bs0[buf][dA0]);
        gload16(bpS1 + t * 64,            &Bs0[buf][dA1]);
    };
    auto stB1 = [&](int buf, int t) {
        gload16(bpS0 + t * 64 + 32 * K,   &Bs1[buf][dA0]);
        gload16(bpS1 + t * 64 + 32 * K,   &Bs1[buf][dA1]);
    };

    int aoff[2][4], boff[2][2];
    #pragma unroll
    for (int kk = 0; kk < 2; ++kk) {
        #pragma unroll
        for (int mi = 0; mi < 4; ++mi) {
            const int lr = wr * 64 + mi * 16 + l15;
            aoff[kk][mi] = lr * 64 + (((kk * 4 + l4) ^ (lr & 7)) * 8);
        }
        #pragma unroll
        for (int nj = 0; nj < 2; ++nj) {
            const int lr = wc * 32 + nj * 16 + l15;
            boff[kk][nj] = lr * 64 + (((kk * 4 + l4) ^ (lr & 7)) * 8);
        }
    }

    f32x4 acc[8][4] = {};
    constexpr int nt = K / 64;

    stA0(0, 0); stB0(0, 0); stB1(0, 0); stA1(0, 0);
    WAIT_VMCNT_4();
    __builtin_amdgcn_s_barrier();

    bf16x8 a[2][4], b01[2][2], b23[2][2];

    for (int t = 0; t < nt; ++t) {
        const int cur = t & 1;
        const int nxt = cur ^ 1;
        const int tn  = (t + 1 < nt) ? t + 1 : 0;

        // phase 1: read A0+B0; stage A0(t+1); MFMA q(0,0)
        #pragma unroll
        for (int kk = 0; kk < 2; ++kk) {
            #pragma unroll
            for (int mi = 0; mi < 4; ++mi)
                a[kk][mi] = *reinterpret_cast<const bf16x8*>(&As0[cur][aoff[kk][mi]]);
            #pragma unroll
            for (int nj = 0; nj < 2; ++nj)
                b01[kk][nj] = *reinterpret_cast<const bf16x8*>(&Bs0[cur][boff[kk][nj]]);
        }
        stA0(nxt, tn);
        WAIT_VMCNT_4();
        __builtin_amdgcn_s_barrier();
        WAIT_LGKM_0();
        __builtin_amdgcn_sched_barrier(0);
        __builtin_amdgcn_s_setprio(1);
        #pragma unroll
        for (int kk = 0; kk < 2; ++kk)
            #pragma unroll
            for (int mi = 0; mi < 4; ++mi)
                #pragma unroll
                for (int nj = 0; nj < 2; ++nj)
                    acc[mi][nj] = __builtin_amdgcn_mfma_f32_16x16x32_bf16(
                        a[kk][mi], b01[kk][nj], acc[mi][nj], 0, 0, 0);
        __builtin_amdgcn_s_setprio(0);
        __builtin_amdgcn_sched_barrier(0);
        __builtin_amdgcn_s_barrier();

        // phase 2: read B1; stage B0(t+1); MFMA q(0,1)
        #pragma unroll
        for (int kk = 0; kk < 2; ++kk)
            #pragma unroll
            for (int nj = 0; nj < 2; ++nj)
                b23[kk][nj] = *reinterpret_cast<const bf16x8*>(&Bs1[cur][boff[kk][nj]]);
        stB0(nxt, tn);
        WAIT_VMCNT_4();
        __builtin_amdgcn_s_barrier();
        WAIT_LGKM_0();
        __builtin_amdgcn_sched_barrier(0);
        __builtin_amdgcn_s_setprio(1);
        #pragma unroll
        for (int kk = 0; kk < 2; ++kk)
            #pragma unroll
            for (int mi = 0; mi < 4; ++mi)
                #pragma unroll
                for (int nj = 0; nj < 2; ++nj)
                    acc[mi][2 + nj] = __builtin_amdgcn_mfma_f32_16x16x32_bf16(
                        a[kk][mi], b23[kk][nj], acc[mi][2 + nj], 0, 0, 0);
        __builtin_amdgcn_s_setprio(0);
        __builtin_amdgcn_sched_barrier(0);
        __builtin_amdgcn_s_barrier();

        // phase 3: read A1; stage B1(t+1); MFMA q(1,0)
        #pragma unroll
        for (int kk = 0; kk < 2; ++kk)
            #pragma unroll
            for (int mi = 0; mi < 4; ++mi)
                a[kk][mi] = *reinterpret_cast<const bf16x8*>(&As1[cur][aoff[kk][mi]]);
        stB1(nxt, tn);
        WAIT_VMCNT_4();
        __builtin_amdgcn_s_barrier();
        WAIT_LGKM_0();
        __builtin_amdgcn_sched_barrier(0);
        __builtin_amdgcn_s_setprio(1);
        #pragma unroll
        for (int kk = 0; kk < 2; ++kk)
            #pragma unroll
            for (int mi = 0; mi < 4; ++mi)
                #pragma unroll
                for (int nj = 0; nj < 2; ++nj)
                    acc[4 + mi][nj] = __builtin_amdgcn_mfma_f32_16x16x32_bf16(
                        a[kk][mi], b01[kk][nj], acc[4 + mi][nj], 0, 0, 0);
        __builtin_amdgcn_s_setprio(0);
        __builtin_amdgcn_sched_barrier(0);
        __builtin_amdgcn_s_barrier();

        // phase 4: stage A1(t+1); MFMA q(1,1)
        stA1(nxt, tn);
        WAIT_VMCNT_4();
        __builtin_amdgcn_s_barrier();
        __builtin_amdgcn_sched_barrier(0);
        __builtin_amdgcn_s_setprio(1);
        #pragma unroll
        for (int kk = 0; kk < 2; ++kk)
            #pragma unroll
            for (int mi = 0; mi < 4; ++mi)
                #pragma unroll
                for (int nj = 0; nj < 2; ++nj)
                    acc[4 + mi][2 + nj] = __builtin_amdgcn_mfma_f32_16x16x32_bf16(
                        a[kk][mi], b23[kk][nj], acc[4 + mi][2 + nj], 0, 0, 0);
        __builtin_amdgcn_s_setprio(0);
        __builtin_amdgcn_sched_barrier(0);
        __builtin_amdgcn_s_barrier();
    }
    WAIT_VMCNT_0();

    float bv[4];
    #pragma unroll
    for (int nf = 0; nf < 4; ++nf)
        bv[nf] = bias[col0 + wc * 64 + nf * 16 + l15];

    if (VSPLIT && col0 >= 2 * C_) {
        #pragma unroll
        for (int mf = 0; mf < 8; ++mf) {
            const int rowb = row0 + wr * 128 + mf * 16 + l4 * 4;
            const int b  = rowb >> 11;
            const int t0 = rowb & (T_ - 1);
            #pragma unroll
            for (int nf = 0; nf < 4; ++nf) {
                const int cv = col0 - 2 * C_ + wc * 64 + nf * 16 + l15;
                u16x4 pack;
                #pragma unroll
                for (int r = 0; r < 4; ++r)
                    pack[r] = f2bf(acc[mf][nf][r] + bv[nf]);
                *reinterpret_cast<u16x4*>(
                    &vt[((size_t)(b * H_ * HS + cv)) * T_ + t0]) = pack;
            }
        }
        return;
    }

    const bool doRope = ROPE && (col0 < 2 * C_);
    const bool doScaleQ = ROPE && (col0 < C_);

    #pragma unroll
    for (int mf = 0; mf < 8; ++mf) {
        #pragma unroll
        for (int r = 0; r < 4; ++r) {
            const int row = row0 + wr * 128 + mf * 16 + l4 * 4 + r;
            const int t   = row & (T_ - 1);
            #pragma unroll
            for (int nf = 0; nf < 4; ++nf) {
                const int col = col0 + wc * 64 + nf * 16 + l15;
                float v = acc[mf][nf][r] + bv[nf];
                if (doRope) {
                    const float partner = __shfl_xor(v, 1);
                    const float2 sc = tab[t * HALF + ((col & 63) >> 1)];
                    v = v * sc.y + ((col & 1) ? partner : -partner) * sc.x;
                }
                if (doScaleQ) v *= QSCALE;
                if (BF16OUT)
                    ((unsigned short*)Cout)[(size_t)row * N + col] = f2bf(v);
                else
                    ((float*)Cout)[(size_t)row * N + col] = v;
            }
        }
    }
}

// ---------------------------------------------------------------------------
// 2-phase 128x128 bf16 MFMA GEMM (R11/R13 version — out-projection).
// ---------------------------------------------------------------------------
template <int N, int K, bool BF16OUT>
__global__ __launch_bounds__(256, 4) void gemm_2ph_kernel(
    const unsigned short* __restrict__ A, const unsigned short* __restrict__ Bt,
    const float* __restrict__ bias, void* __restrict__ Cout, int nbx, int nby)
{
    __shared__ unsigned short As[2][128 * 32];
    __shared__ unsigned short Bs[2][128 * 32];

    const int tid  = threadIdx.x;
    const int lane = tid & 63;
    const int wave = tid >> 6;
    const int wr   = wave >> 1;
    const int wc   = wave & 1;
    const int l15  = lane & 15;
    const int l4   = lane >> 4;

    const int bid  = blockIdx.x;
    const int xcd  = bid & 7;
    const int w    = bid >> 3;
    const int cpr  = nbx >> 1;
    const int rpr  = nby >> 2;
    const int by   = ((xcd >> 1) * rpr) + (w / cpr);
    const int bx   = ((xcd & 1) * cpr) + (w % cpr);
    const int row0 = by * 128;
    const int col0 = bx * 128;

    f32x4 acc[4][4] = {};

    const int ar  = tid >> 2;
    const int sl  = tid & 3;
    const int swz = (sl ^ ((ar >> 1) & 3)) * 8;
    const unsigned short* ap = &A[(size_t)(row0 + ar) * K + swz];
    const unsigned short* bp = &Bt[(size_t)(col0 + ar) * K + swz];

    auto stage = [&](int buf, int t) {
        const unsigned short* a0 = ap + t * 32;
        const unsigned short* b0 = bp + t * 32;
        gload16(a0,          &As[buf][tid * 8]);
        gload16(a0 + 64 * K, &As[buf][(tid + 256) * 8]);
        gload16(b0,          &Bs[buf][tid * 8]);
        gload16(b0 + 64 * K, &Bs[buf][(tid + 256) * 8]);
    };

    int aoff[4], boff[4];
    #pragma unroll
    for (int mi = 0; mi < 4; ++mi) {
        const int lr = wr * 64 + mi * 16 + l15;
        aoff[mi] = lr * 32 + ((l4 ^ ((lr >> 1) & 3)) * 8);
    }
    #pragma unroll
    for (int nj = 0; nj < 4; ++nj) {
        const int lr = wc * 64 + nj * 16 + l15;
        boff[nj] = lr * 32 + ((l4 ^ ((lr >> 1) & 3)) * 8);
    }

    constexpr int nt = K / 32;
    stage(0, 0);

    for (int t = 0; t < nt; ++t) {
        const int cur = t & 1;
        if (t + 1 < nt) {
            stage(cur ^ 1, t + 1);
            WAIT_VMCNT_4();
        } else {
            WAIT_VMCNT_0();
        }
        __builtin_amdgcn_s_barrier();
        __builtin_amdgcn_sched_barrier(0);

        bf16x8 a[4], b[4];
        #pragma unroll
        for (int mi = 0; mi < 4; ++mi)
            a[mi] = *reinterpret_cast<const bf16x8*>(&As[cur][aoff[mi]]);
        #pragma unroll
        for (int nj = 0; nj < 4; ++nj)
            b[nj] = *reinterpret_cast<const bf16x8*>(&Bs[cur][boff[nj]]);
        #pragma unroll
        for (int mi = 0; mi < 4; ++mi)
            #pragma unroll
            for (int nj = 0; nj < 4; ++nj)
                acc[mi][nj] = __builtin_amdgcn_mfma_f32_16x16x32_bf16(
                    a[mi], b[nj], acc[mi][nj], 0, 0, 0);

        __builtin_amdgcn_sched_barrier(0);
        __builtin_amdgcn_s_barrier();
    }

    float bv[4];
    #pragma unroll
    for (int nj = 0; nj < 4; ++nj)
        bv[nj] = bias[col0 + wc * 64 + nj * 16 + l15];

    #pragma unroll
    for (int mi = 0; mi < 4; ++mi) {
        #pragma unroll
        for (int r = 0; r < 4; ++r) {
            const int row = row0 + wr * 64 + mi * 16 + l4 * 4 + r;
            #pragma unroll
            for (int nj = 0; nj < 4; ++nj) {
                const int col = col0 + wc * 64 + nj * 16 + l15;
                const float v = acc[mi][nj][r] + bv[nj];
                if (BF16OUT)
                    ((unsigned short*)Cout)[(size_t)row * N + col] = f2bf(v);
                else
                    ((float*)Cout)[(size_t)row * N + col] = v;
            }
        }
    }
}

// ---------------------------------------------------------------------------
// Flash attention v6: KVBLK=64, 4 blocks/CU (32KB LDS) for doubled VALU
// latency hiding. Same swapped-operand 32x32 structure, paired causal
// q-tiles, dbuf K/V with counted vmcnt(4), merged 64-j in-register softmax,
// raw exp2, permlane32_swap, Q pre-scaled.
// ---------------------------------------------------------------------------
__global__ __launch_bounds__(256, 4) void attn_mfma6_kernel(
    const unsigned short* __restrict__ qkv,   // roped+scaled qkv, bf16
    const unsigned short* __restrict__ vt,    // V^T global [(b*H+h)*64+d][T]
    unsigned short* __restrict__ out)         // [B*T][C] bf16
{
    __shared__ unsigned short Ks[2][64 * 64];   // [j][d], swizzled (8KB each)
    __shared__ unsigned short Vs[2][64 * 64];   // [d][j], swizzled (8KB each)

    const int idx = blockIdx.x;
    const int bh  = idx & 63;                 // b*16 + h
    const int qp  = idx >> 6;                 // 0..7
    const int b   = bh >> 4;
    const int h   = bh & 15;
    const int qtA = qp;
    const int qtB = 15 - qp;

    const int tid  = threadIdx.x;
    const int lane = tid & 63;
    const int w    = tid >> 6;
    const int l31  = lane & 31;
    const int hi   = lane >> 5;

    const int qwA = qtA * 128 + w * 32;
    const int qgA = qwA + l31;
    const int qwB = qtB * 128 + w * 32;
    const int qgB = qwB + l31;

    bf16x8 aqA[4], aqB[4];
    {
        const unsigned short* qpA = &qkv[(size_t)(b * T_ + qgA) * QKV_N + h * HS + hi * 8];
        const unsigned short* qpB = &qkv[(size_t)(b * T_ + qgB) * QKV_N + h * HS + hi * 8];
        #pragma unroll
        for (int kc = 0; kc < 4; ++kc) {
            aqA[kc] = *reinterpret_cast<const bf16x8*>(qpA + kc * 16);
            aqB[kc] = *reinterpret_cast<const bf16x8*>(qpB + kc * 16);
        }
    }

    f32x16 accA0 = {}, accA1 = {}, accB0 = {}, accB1 = {};
    float mA = -INFINITY, lA = 0.f, mB = -INFINITY, lB = 0.f;

    // stage one 64-j chunk: K 64x64 (2 loads) + V 64x64 (2 loads)
    auto stageKV = [&](int buf, int it) {
        #pragma unroll
        for (int n = 0; n < 2; ++n) {
            const int r  = n * 32 + (tid >> 3);
            const int sk = ((tid & 7) ^ (r & 7)) * 8;
            gload16(&qkv[(size_t)(b * T_ + it * 64 + r) * QKV_N + C_ + h * HS + sk],
                    &Ks[buf][(n * 256 + tid) * 8]);
        }
        #pragma unroll
        for (int n = 0; n < 2; ++n) {
            const int d  = n * 32 + (tid >> 3);
            const int sv = ((tid & 7) ^ (d & 7)) * 8;
            gload16(&vt[((size_t)(bh * HS + d)) * T_ + it * 64 + sv],
                    &Vs[buf][(n * 256 + tid) * 8]);
        }
    };

    // merged 64-j processing (2 groups of 32)
    auto process = [&](const unsigned short* Kb, const unsigned short* Vb,
                       const bf16x8* aq, f32x16& a0, f32x16& a1,
                       float& mval, float& lval, int qw, int qg, int kbase) {
        f32x16 s[2] = {};
        __builtin_amdgcn_s_setprio(1);
        #pragma unroll
        for (int kc = 0; kc < 4; ++kc) {
            const int bo = kc * 32 + hi * 16;       // byte offset in 128B K row
            #pragma unroll
            for (int g = 0; g < 2; ++g) {
                const int rj = g * 32 + l31;
                const bf16x8 ak = *reinterpret_cast<const bf16x8*>(
                    &Kb[rj * 64 + ((bo ^ ((rj & 7) << 4)) >> 1)]);
                s[g] = __builtin_amdgcn_mfma_f32_32x32x16_bf16(ak, aq[kc], s[g], 0, 0, 0);
            }
        }
        __builtin_amdgcn_s_setprio(0);

        if (kbase + 63 > qw) {
            #pragma unroll
            for (int g = 0; g < 2; ++g) {
                #pragma unroll
                for (int r = 0; r < 16; ++r) {
                    const int j0 = kbase + g * 32 + (r & 3) + 8 * (r >> 2) + 4 * hi;
                    if (j0 > qg) s[g][r] = -INFINITY;
                }
            }
        }

        float tg[2];
        #pragma unroll
        for (int g = 0; g < 2; ++g) {
            const float v0 = FMAX3(s[g][0],  s[g][1],  s[g][2]);
            const float v1 = FMAX3(s[g][3],  s[g][4],  s[g][5]);
            const float v2 = FMAX3(s[g][6],  s[g][7],  s[g][8]);
            const float v3 = FMAX3(s[g][9],  s[g][10], s[g][11]);
            const float v4 = FMAX3(s[g][12], s[g][13], s[g][14]);
            tg[g] = fmaxf(FMAX3(v0, v1, v2), FMAX3(v3, v4, s[g][15]));
        }
        float tm = fmaxf(tg[0], tg[1]);
        tm = fmaxf(tm, __shfl_xor(tm, 32));

        const bool upd = (tm > mval + 8.f);          // defer-max THR=8 (log2)
        if (__ballot(upd)) {
            const float nm = upd ? tm : mval;
            const float sf = EXP2(mval - nm);
            lval *= sf;
            #pragma unroll
            for (int r = 0; r < 16; ++r) { a0[r] *= sf; a1[r] *= sf; }
            mval = nm;
        }

        float rs0 = 0.f, rs1 = 0.f;
        #pragma unroll
        for (int r = 0; r < 16; ++r) {
            s[0][r] = EXP2(s[0][r] - mval); rs0 += s[0][r];
            s[1][r] = EXP2(s[1][r] - mval); rs1 += s[1][r];
        }
        float rs = rs0 + rs1;
        rs += __shfl_xor(rs, 32);
        lval += rs;

        // P fragments + PV over 64 j
        #pragma unroll
        for (int g = 0; g < 2; ++g) {
            #pragma unroll
            for (int c = 0; c < 2; ++c) {
                const int e = c * 8;
                const unsigned pa = cvtpk_bf16(s[g][e + 0], s[g][e + 1]);
                const unsigned pb = cvtpk_bf16(s[g][e + 2], s[g][e + 3]);
                const unsigned pc = cvtpk_bf16(s[g][e + 4], s[g][e + 5]);
                const unsigned pd = cvtpk_bf16(s[g][e + 6], s[g][e + 7]);
                int4 bw;
#if __has_builtin(__builtin_amdgcn_permlane32_swap)
                const u32x2 rx = __builtin_amdgcn_permlane32_swap(pa, pc, false, false);
                const u32x2 ry = __builtin_amdgcn_permlane32_swap(pb, pd, false, false);
                bw.x = (int)rx[0]; bw.y = (int)ry[0];
                bw.z = (int)rx[1]; bw.w = (int)ry[1];
#else
                const unsigned pas = (unsigned)__shfl_xor((int)pa, 32);
                const unsigned pbs = (unsigned)__shfl_xor((int)pb, 32);
                const unsigned pcs = (unsigned)__shfl_xor((int)pc, 32);
                const unsigned pds = (unsigned)__shfl_xor((int)pd, 32);
                bw.x = (int)(hi ? pcs : pa);
                bw.y = (int)(hi ? pds : pb);
                bw.z = (int)(hi ? pc  : pas);
                bw.w = (int)(hi ? pd  : pbs);
#endif
                const bf16x8 bfrag = __builtin_bit_cast(bf16x8, bw);

                const int lslot = (g * 2 + c) * 2 + hi;   // 16B slot in 128B Vs row
                const int d0 = l31;
                const bf16x8 av0 = *reinterpret_cast<const bf16x8*>(
                    &Vb[d0 * 64 + ((lslot ^ (d0 & 7)) * 8)]);
                const int d1 = 32 + l31;
                const bf16x8 av1 = *reinterpret_cast<const bf16x8*>(
                    &Vb[d1 * 64 + ((lslot ^ (d1 & 7)) * 8)]);
                __builtin_amdgcn_s_setprio(1);
                a0 = __builtin_amdgcn_mfma_f32_32x32x16_bf16(av0, bfrag, a0, 0, 0, 0);
                a1 = __builtin_amdgcn_mfma_f32_32x32x16_bf16(av1, bfrag, a1, 0, 0, 0);
                __builtin_amdgcn_s_setprio(0);
            }
        }
    };

    const int nIter = 2 * qtB + 2;                   // 64-wide k chunks
    stageKV(0, 0);
    for (int it = 0; it < nIter; ++it) {
        const int cur = it & 1;
        __builtin_amdgcn_sched_barrier(0);
        if (it + 1 < nIter) {
            stageKV(cur ^ 1, it + 1);
            WAIT_VMCNT_4();
        } else {
            WAIT_VMCNT_0();
        }
        __builtin_amdgcn_s_barrier();
        __builtin_amdgcn_sched_barrier(0);

        const unsigned short* Kb = &Ks[cur][0];
        const unsigned short* Vb = &Vs[cur][0];
        const int kbase = it * 64;
        if (kbase <= qwA + 31)
            process(Kb, Vb, aqA, accA0, accA1, mA, lA, qwA, qgA, kbase);
        if (kbase <= qwB + 31)
            process(Kb, Vb, aqB, accB0, accB1, mB, lB, qwB, qgB, kbase);
        __builtin_amdgcn_sched_barrier(0);
        __builtin_amdgcn_s_barrier();
    }

    {
        const float inv = 1.0f / lA;
        unsigned short* orow = &out[(size_t)(b * T_ + qgA) * C_ + h * HS];
        #pragma unroll
        for (int g = 0; g < 4; ++g) {
            uint2 wv;
            wv.x = cvtpk_bf16(accA0[4 * g + 0] * inv, accA0[4 * g + 1] * inv);
            wv.y = cvtpk_bf16(accA0[4 * g + 2] * inv, accA0[4 * g + 3] * inv);
            *reinterpret_cast<uint2*>(&orow[8 * g + 4 * hi]) = wv;
            uint2 wv1;
            wv1.x = cvtpk_bf16(accA1[4 * g + 0] * inv, accA1[4 * g + 1] * inv);
            wv1.y = cvtpk_bf16(accA1[4 * g + 2] * inv, accA1[4 * g + 3] * inv);
            *reinterpret_cast<uint2*>(&orow[32 + 8 * g + 4 * hi]) = wv1;
        }
    }
    {
        const float inv = 1.0f / lB;
        unsigned short* orow = &out[(size_t)(b * T_ + qgB) * C_ + h * HS];
        #pragma unroll
        for (int g = 0; g < 4; ++g) {
            uint2 wv;
            wv.x = cvtpk_bf16(accB0[4 * g + 0] * inv, accB0[4 * g + 1] * inv);
            wv.y = cvtpk_bf16(accB0[4 * g + 2] * inv, accB0[4 * g + 3] * inv);
            *reinterpret_cast<uint2*>(&orow[8 * g + 4 * hi]) = wv;
            uint2 wv1;
            wv1.x = cvtpk_bf16(accB1[4 * g + 0] * inv, accB1[4 * g + 1] * inv);
            wv1.y = cvtpk_bf16(accB1[4 * g + 2] * inv, accB1[4 * g + 3] * inv);
            *reinterpret_cast<uint2*>(&orow[32 + 8 * g + 4 * hi]) = wv1;
        }
    }
}

// ---------------------------------------------------------------------------
extern "C" void kernel_launch(void* const* d_in, const int* in_sizes, int n_in,
                              void* d_out, int out_size, void* d_ws, size_t ws_size,
                              hipStream_t stream)
{
    const float* x    = (const float*)d_in[0];   // [B,T,C]
    const float* Wqkv = (const float*)d_in[1];   // [C,3C]
    const float* bqkv = (const float*)d_in[2];   // [3C]
    const float* Wout = (const float*)d_in[3];   // [C,C]
    const float* bout = (const float*)d_in[4];   // [C]
    float* out = (float*)d_out;                  // [B,T,C] fp32

    char* ws = (char*)d_ws;
    unsigned short* qkvb  = (unsigned short*)ws;                       // 50,331,648
    unsigned short* xb    = (unsigned short*)(ws + 50331648);          // 16,777,216
    unsigned short* attnb = (unsigned short*)(ws + 67108864);          // 16,777,216
    unsigned short* vt_g  = (unsigned short*)(ws + 83886080);          // 16,777,216
    unsigned short* Wqkvt = (unsigned short*)(ws + 100663296);         //  6,291,456
    unsigned short* Woutt = (unsigned short*)(ws + 106954752);         //  2,097,152
    float2* tab           = (float2*)(ws + 109051904);                 //    524,288

    // 1) fused prep: x cast + rope table + both weight transposes
    prep2_kernel<<<8448, 256, 0, stream>>>(x, xb, tab, Wqkv, Wout, Wqkvt, Woutt);

    // 2) QKV projection: 8-phase 256x256 (best measured for this shape)
    gemm_8ph_kernel<QKV_N, C_, true, true, true>
        <<<(M_ / 256) * (QKV_N / 256), 512, 0, stream>>>(
        xb, Wqkvt, bqkv, tab, qkvb, vt_g, QKV_N / 256, M_ / 256);

    // 3) attention -> attnb [B,T,C] bf16 (KVBLK=64, 4 blocks/CU)
    attn_mfma6_kernel<<<B_ * H_ * (T_ / 256), 256, 0, stream>>>(qkvb, vt_g, attnb);

    // 4) output projection: 2-phase 128x128 (512 blocks, 4/CU)
    gemm_2ph_kernel<C_, C_, false>
        <<<(M_ / 128) * (C_ / 128), 256, 0, stream>>>(
        attnb, Woutt, bout, out, C_ / 128, M_ / 128);
}

// Round 18
// 166.847 us; speedup vs baseline: 1.4185x; 1.4185x over previous
//
#include <hip/hip_runtime.h>
#include <math.h>

// Problem constants (B=4, T=2048, C=1024, H=16, hs=64)
#define B_   4
#define T_   2048
#define C_   1024
#define H_   16
#define HS   64
#define HALF 32
#define QKV_N (3 * C_)      // 3072
#define M_    (B_ * T_)     // 8192

using bf16x8 = __attribute__((ext_vector_type(8))) short;
using f32x4  = __attribute__((ext_vector_type(4))) float;
using f32x16 = __attribute__((ext_vector_type(16))) float;
using u16x4  = __attribute__((ext_vector_type(4))) unsigned short;
using u32x2  = __attribute__((ext_vector_type(2))) unsigned int;

__device__ __forceinline__ unsigned short f2bf(float f) {
    unsigned u = __builtin_bit_cast(unsigned, f);
    u = (u + 0x7FFFu + ((u >> 16) & 1u)) >> 16;
    return (unsigned short)u;
}
__device__ __forceinline__ float bf2f(unsigned short b) {
    return __builtin_bit_cast(float, (unsigned)b << 16);
}
__device__ __forceinline__ unsigned cvtpk_bf16(float lo, float hi_) {
    unsigned r;
    asm("v_cvt_pk_bf16_f32 %0, %1, %2" : "=v"(r) : "v"(lo), "v"(hi_));
    return r;
}
__device__ __forceinline__ void gload16(const void* g, void* l) {
    __builtin_amdgcn_global_load_lds(
        (const __attribute__((address_space(1))) unsigned int*)g,
        (__attribute__((address_space(3))) unsigned int*)l, 16, 0, 0);
}
#define WAIT_VMCNT_8() asm volatile("s_waitcnt vmcnt(8)" ::: "memory")
#define WAIT_VMCNT_4() asm volatile("s_waitcnt vmcnt(4)" ::: "memory")
#define WAIT_VMCNT_0() asm volatile("s_waitcnt vmcnt(0)" ::: "memory")
#define WAIT_LGKM_0()  asm volatile("s_waitcnt lgkmcnt(0)" ::: "memory")

#if __has_builtin(__builtin_amdgcn_exp2f)
#define EXP2(x) __builtin_amdgcn_exp2f(x)
#else
#define EXP2(x) exp2f(x)
#endif
#define FMAX3(a, b, c) fmaxf(fmaxf((a), (b)), (c))

#define QSCALE 0.18033688011112042f   // 0.125 * log2(e), folded into Q

// ---------------------------------------------------------------------------
// prep2: blocks [0,4096): fp32->bf16 cast of x
//        blocks [4096,4352): RoPE sin/cos table
//        blocks [4352,7424): Wqkv transpose+cast
//        blocks [7424,8448): Wout transpose+cast
// ---------------------------------------------------------------------------
__global__ __launch_bounds__(256) void prep2_kernel(
    const float* __restrict__ x, unsigned short* __restrict__ xb,
    float2* __restrict__ tab,
    const float* __restrict__ Wqkv, const float* __restrict__ Wout,
    unsigned short* __restrict__ Wqkvt, unsigned short* __restrict__ Woutt)
{
    __shared__ float tile[32][33];
    const int bid = blockIdx.x;
    if (bid < 4096) {
        const size_t i = ((size_t)bid * 256 + threadIdx.x) * 8;
        const float4 a = *reinterpret_cast<const float4*>(&x[i]);
        const float4 b = *reinterpret_cast<const float4*>(&x[i + 4]);
        bf16x8 v;
        v[0] = f2bf(a.x); v[1] = f2bf(a.y); v[2] = f2bf(a.z); v[3] = f2bf(a.w);
        v[4] = f2bf(b.x); v[5] = f2bf(b.y); v[6] = f2bf(b.z); v[7] = f2bf(b.w);
        *reinterpret_cast<bf16x8*>(&xb[i]) = v;
        return;
    }
    if (bid < 4352) {
        const int idx = (bid - 4096) * 256 + threadIdx.x;   // 0 .. T_*HALF-1
        const int t = idx / HALF;
        const int i = idx % HALF;
        const float theta = powf(10000.0f, -(float)i / (float)HALF);
        const float ang = (float)t * theta;
        float sn, cs;
        sincosf(ang, &sn, &cs);
        tab[idx] = make_float2(sn, cs);
        return;
    }
    const float* W;
    unsigned short* Wt;
    int N, k0, n0;
    if (bid < 7424) {
        const int r0 = bid - 4352;
        W = Wqkv; Wt = Wqkvt; N = QKV_N;
        n0 = (r0 % 96) * 32; k0 = (r0 / 96) * 32;
    } else {
        const int r0 = bid - 7424;
        W = Wout; Wt = Woutt; N = C_;
        n0 = (r0 % 32) * 32; k0 = (r0 / 32) * 32;
    }
    const int K = C_;
    const int r = threadIdx.x / 32;
    const int c = threadIdx.x % 32;
    #pragma unroll
    for (int it = 0; it < 4; ++it)
        tile[r + it * 8][c] = W[(size_t)(k0 + r + it * 8) * N + n0 + c];
    __syncthreads();
    #pragma unroll
    for (int it = 0; it < 4; ++it)
        Wt[(size_t)(n0 + r + it * 8) * K + k0 + c] = f2bf(tile[c][r + it * 8]);
}

// ---------------------------------------------------------------------------
// 8-phase bf16 MFMA GEMM (R12/R13 version — QKV). BM=BN=256, BK=64,
// 512 threads = 8 waves, per-wave 128x64 (acc[8][4]).
// ---------------------------------------------------------------------------
template <int N, int K, bool BF16OUT, bool ROPE, bool VSPLIT>
__global__ __launch_bounds__(512, 1) void gemm_8ph_kernel(
    const unsigned short* __restrict__ A, const unsigned short* __restrict__ Bt,
    const float* __restrict__ bias, const float2* __restrict__ tab,
    void* __restrict__ Cout, unsigned short* __restrict__ vt, int nbx, int nby)
{
    __shared__ unsigned short As0[2][128 * 64];
    __shared__ unsigned short As1[2][128 * 64];
    __shared__ unsigned short Bs0[2][128 * 64];
    __shared__ unsigned short Bs1[2][128 * 64];

    const int tid  = threadIdx.x;
    const int lane = tid & 63;
    const int wave = tid >> 6;        // 0..7
    const int wr   = wave >> 2;       // 0..1 : M half (128 rows)
    const int wc   = wave & 3;        // 0..3 : N quarter (64 cols)
    const int l15  = lane & 15;
    const int l4   = lane >> 4;

    const int bid  = blockIdx.x;
    const int xcd  = bid & 7;
    const int w    = bid >> 3;
    const int cpr  = nbx >> 1;
    const int rpr  = nby >> 2;
    const int by   = ((xcd >> 1) * rpr) + (w / cpr);
    const int bx   = ((xcd & 1) * cpr) + (w % cpr);
    const int row0 = by * 256;
    const int col0 = bx * 256;

    const int lr0 = tid >> 3,          sl0 = tid & 7;
    const int lr1 = (tid + 512) >> 3,  sl1 = (tid + 512) & 7;
    const int kc0 = (sl0 ^ (lr0 & 7)) * 8;
    const int kc1 = (sl1 ^ (lr1 & 7)) * 8;
    const int dA0 = tid * 8;
    const int dA1 = (tid + 512) * 8;
    const unsigned short* apS0 = &A[(size_t)(row0 + (lr0 >> 6) * 128 + (lr0 & 63)) * K + kc0];
    const unsigned short* apS1 = &A[(size_t)(row0 + (lr1 >> 6) * 128 + (lr1 & 63)) * K + kc1];
    const unsigned short* bpS0 = &Bt[(size_t)(col0 + (lr0 >> 5) * 64 + (lr0 & 31)) * K + kc0];
    const unsigned short* bpS1 = &Bt[(size_t)(col0 + (lr1 >> 5) * 64 + (lr1 & 31)) * K + kc1];

    auto stA0 = [&](int buf, int t) {
        gload16(apS0 + t * 64,            &As0[buf][dA0]);
        gload16(apS1 + t * 64,            &As0[buf][dA1]);
    };
    auto stA1 = [&](int buf, int t) {
        gload16(apS0 + t * 64 + 64 * K,   &As1[buf][dA0]);
        gload16(apS1 + t * 64 + 64 * K,   &As1[buf][dA1]);
    };
    auto stB0 = [&](int buf, int t) {
        gload16(bpS0 + t * 64,            &Bs0[buf][dA0]);
        gload16(bpS1 + t * 64,            &Bs0[buf][dA1]);
    };
    auto stB1 = [&](int buf, int t) {
        gload16(bpS0 + t * 64 + 32 * K,   &Bs1[buf][dA0]);
        gload16(bpS1 + t * 64 + 32 * K,   &Bs1[buf][dA1]);
    };

    int aoff[2][4], boff[2][2];
    #pragma unroll
    for (int kk = 0; kk < 2; ++kk) {
        #pragma unroll
        for (int mi = 0; mi < 4; ++mi) {
            const int lr = wr * 64 + mi * 16 + l15;
            aoff[kk][mi] = lr * 64 + (((kk * 4 + l4) ^ (lr & 7)) * 8);
        }
        #pragma unroll
        for (int nj = 0; nj < 2; ++nj) {
            const int lr = wc * 32 + nj * 16 + l15;
            boff[kk][nj] = lr * 64 + (((kk * 4 + l4) ^ (lr & 7)) * 8);
        }
    }

    f32x4 acc[8][4] = {};
    constexpr int nt = K / 64;

    stA0(0, 0); stB0(0, 0); stB1(0, 0); stA1(0, 0);
    WAIT_VMCNT_4();
    __builtin_amdgcn_s_barrier();

    bf16x8 a[2][4], b01[2][2], b23[2][2];

    for (int t = 0; t < nt; ++t) {
        const int cur = t & 1;
        const int nxt = cur ^ 1;
        const int tn  = (t + 1 < nt) ? t + 1 : 0;

        // phase 1: read A0+B0; stage A0(t+1); MFMA q(0,0)
        #pragma unroll
        for (int kk = 0; kk < 2; ++kk) {
            #pragma unroll
            for (int mi = 0; mi < 4; ++mi)
                a[kk][mi] = *reinterpret_cast<const bf16x8*>(&As0[cur][aoff[kk][mi]]);
            #pragma unroll
            for (int nj = 0; nj < 2; ++nj)
                b01[kk][nj] = *reinterpret_cast<const bf16x8*>(&Bs0[cur][boff[kk][nj]]);
        }
        stA0(nxt, tn);
        WAIT_VMCNT_4();
        __builtin_amdgcn_s_barrier();
        WAIT_LGKM_0();
        __builtin_amdgcn_sched_barrier(0);
        __builtin_amdgcn_s_setprio(1);
        #pragma unroll
        for (int kk = 0; kk < 2; ++kk)
            #pragma unroll
            for (int mi = 0; mi < 4; ++mi)
                #pragma unroll
                for (int nj = 0; nj < 2; ++nj)
                    acc[mi][nj] = __builtin_amdgcn_mfma_f32_16x16x32_bf16(
                        a[kk][mi], b01[kk][nj], acc[mi][nj], 0, 0, 0);
        __builtin_amdgcn_s_setprio(0);
        __builtin_amdgcn_sched_barrier(0);
        __builtin_amdgcn_s_barrier();

        // phase 2: read B1; stage B0(t+1); MFMA q(0,1)
        #pragma unroll
        for (int kk = 0; kk < 2; ++kk)
            #pragma unroll
            for (int nj = 0; nj < 2; ++nj)
                b23[kk][nj] = *reinterpret_cast<const bf16x8*>(&Bs1[cur][boff[kk][nj]]);
        stB0(nxt, tn);
        WAIT_VMCNT_4();
        __builtin_amdgcn_s_barrier();
        WAIT_LGKM_0();
        __builtin_amdgcn_sched_barrier(0);
        __builtin_amdgcn_s_setprio(1);
        #pragma unroll
        for (int kk = 0; kk < 2; ++kk)
            #pragma unroll
            for (int mi = 0; mi < 4; ++mi)
                #pragma unroll
                for (int nj = 0; nj < 2; ++nj)
                    acc[mi][2 + nj] = __builtin_amdgcn_mfma_f32_16x16x32_bf16(
                        a[kk][mi], b23[kk][nj], acc[mi][2 + nj], 0, 0, 0);
        __builtin_amdgcn_s_setprio(0);
        __builtin_amdgcn_sched_barrier(0);
        __builtin_amdgcn_s_barrier();

        // phase 3: read A1; stage B1(t+1); MFMA q(1,0)
        #pragma unroll
        for (int kk = 0; kk < 2; ++kk)
            #pragma unroll
            for (int mi = 0; mi < 4; ++mi)
                a[kk][mi] = *reinterpret_cast<const bf16x8*>(&As1[cur][aoff[kk][mi]]);
        stB1(nxt, tn);
        WAIT_VMCNT_4();
        __builtin_amdgcn_s_barrier();
        WAIT_LGKM_0();
        __builtin_amdgcn_sched_barrier(0);
        __builtin_amdgcn_s_setprio(1);
        #pragma unroll
        for (int kk = 0; kk < 2; ++kk)
            #pragma unroll
            for (int mi = 0; mi < 4; ++mi)
                #pragma unroll
                for (int nj = 0; nj < 2; ++nj)
                    acc[4 + mi][nj] = __builtin_amdgcn_mfma_f32_16x16x32_bf16(
                        a[kk][mi], b01[kk][nj], acc[4 + mi][nj], 0, 0, 0);
        __builtin_amdgcn_s_setprio(0);
        __builtin_amdgcn_sched_barrier(0);
        __builtin_amdgcn_s_barrier();

        // phase 4: stage A1(t+1); MFMA q(1,1)
        stA1(nxt, tn);
        WAIT_VMCNT_4();
        __builtin_amdgcn_s_barrier();
        __builtin_amdgcn_sched_barrier(0);
        __builtin_amdgcn_s_setprio(1);
        #pragma unroll
        for (int kk = 0; kk < 2; ++kk)
            #pragma unroll
            for (int mi = 0; mi < 4; ++mi)
                #pragma unroll
                for (int nj = 0; nj < 2; ++nj)
                    acc[4 + mi][2 + nj] = __builtin_amdgcn_mfma_f32_16x16x32_bf16(
                        a[kk][mi], b23[kk][nj], acc[4 + mi][2 + nj], 0, 0, 0);
        __builtin_amdgcn_s_setprio(0);
        __builtin_amdgcn_sched_barrier(0);
        __builtin_amdgcn_s_barrier();
    }
    WAIT_VMCNT_0();

    float bv[4];
    #pragma unroll
    for (int nf = 0; nf < 4; ++nf)
        bv[nf] = bias[col0 + wc * 64 + nf * 16 + l15];

    if (VSPLIT && col0 >= 2 * C_) {
        #pragma unroll
        for (int mf = 0; mf < 8; ++mf) {
            const int rowb = row0 + wr * 128 + mf * 16 + l4 * 4;
            const int b  = rowb >> 11;
            const int t0 = rowb & (T_ - 1);
            #pragma unroll
            for (int nf = 0; nf < 4; ++nf) {
                const int cv = col0 - 2 * C_ + wc * 64 + nf * 16 + l15;
                u16x4 pack;
                #pragma unroll
                for (int r = 0; r < 4; ++r)
                    pack[r] = f2bf(acc[mf][nf][r] + bv[nf]);
                *reinterpret_cast<u16x4*>(
                    &vt[((size_t)(b * H_ * HS + cv)) * T_ + t0]) = pack;
            }
        }
        return;
    }

    const bool doRope = ROPE && (col0 < 2 * C_);
    const bool doScaleQ = ROPE && (col0 < C_);

    #pragma unroll
    for (int mf = 0; mf < 8; ++mf) {
        #pragma unroll
        for (int r = 0; r < 4; ++r) {
            const int row = row0 + wr * 128 + mf * 16 + l4 * 4 + r;
            const int t   = row & (T_ - 1);
            #pragma unroll
            for (int nf = 0; nf < 4; ++nf) {
                const int col = col0 + wc * 64 + nf * 16 + l15;
                float v = acc[mf][nf][r] + bv[nf];
                if (doRope) {
                    const float partner = __shfl_xor(v, 1);
                    const float2 sc = tab[t * HALF + ((col & 63) >> 1)];
                    v = v * sc.y + ((col & 1) ? partner : -partner) * sc.x;
                }
                if (doScaleQ) v *= QSCALE;
                if (BF16OUT)
                    ((unsigned short*)Cout)[(size_t)row * N + col] = f2bf(v);
                else
                    ((float*)Cout)[(size_t)row * N + col] = v;
            }
        }
    }
}

// ---------------------------------------------------------------------------
// 2-phase 128x128 bf16 MFMA GEMM (R11/R13 version — out-projection).
// ---------------------------------------------------------------------------
template <int N, int K, bool BF16OUT>
__global__ __launch_bounds__(256, 4) void gemm_2ph_kernel(
    const unsigned short* __restrict__ A, const unsigned short* __restrict__ Bt,
    const float* __restrict__ bias, void* __restrict__ Cout, int nbx, int nby)
{
    __shared__ unsigned short As[2][128 * 32];
    __shared__ unsigned short Bs[2][128 * 32];

    const int tid  = threadIdx.x;
    const int lane = tid & 63;
    const int wave = tid >> 6;
    const int wr   = wave >> 1;
    const int wc   = wave & 1;
    const int l15  = lane & 15;
    const int l4   = lane >> 4;

    const int bid  = blockIdx.x;
    const int xcd  = bid & 7;
    const int w    = bid >> 3;
    const int cpr  = nbx >> 1;
    const int rpr  = nby >> 2;
    const int by   = ((xcd >> 1) * rpr) + (w / cpr);
    const int bx   = ((xcd & 1) * cpr) + (w % cpr);
    const int row0 = by * 128;
    const int col0 = bx * 128;

    f32x4 acc[4][4] = {};

    const int ar  = tid >> 2;
    const int sl  = tid & 3;
    const int swz = (sl ^ ((ar >> 1) & 3)) * 8;
    const unsigned short* ap = &A[(size_t)(row0 + ar) * K + swz];
    const unsigned short* bp = &Bt[(size_t)(col0 + ar) * K + swz];

    auto stage = [&](int buf, int t) {
        const unsigned short* a0 = ap + t * 32;
        const unsigned short* b0 = bp + t * 32;
        gload16(a0,          &As[buf][tid * 8]);
        gload16(a0 + 64 * K, &As[buf][(tid + 256) * 8]);
        gload16(b0,          &Bs[buf][tid * 8]);
        gload16(b0 + 64 * K, &Bs[buf][(tid + 256) * 8]);
    };

    int aoff[4], boff[4];
    #pragma unroll
    for (int mi = 0; mi < 4; ++mi) {
        const int lr = wr * 64 + mi * 16 + l15;
        aoff[mi] = lr * 32 + ((l4 ^ ((lr >> 1) & 3)) * 8);
    }
    #pragma unroll
    for (int nj = 0; nj < 4; ++nj) {
        const int lr = wc * 64 + nj * 16 + l15;
        boff[nj] = lr * 32 + ((l4 ^ ((lr >> 1) & 3)) * 8);
    }

    constexpr int nt = K / 32;
    stage(0, 0);

    for (int t = 0; t < nt; ++t) {
        const int cur = t & 1;
        if (t + 1 < nt) {
            stage(cur ^ 1, t + 1);
            WAIT_VMCNT_4();
        } else {
            WAIT_VMCNT_0();
        }
        __builtin_amdgcn_s_barrier();
        __builtin_amdgcn_sched_barrier(0);

        bf16x8 a[4], b[4];
        #pragma unroll
        for (int mi = 0; mi < 4; ++mi)
            a[mi] = *reinterpret_cast<const bf16x8*>(&As[cur][aoff[mi]]);
        #pragma unroll
        for (int nj = 0; nj < 4; ++nj)
            b[nj] = *reinterpret_cast<const bf16x8*>(&Bs[cur][boff[nj]]);
        #pragma unroll
        for (int mi = 0; mi < 4; ++mi)
            #pragma unroll
            for (int nj = 0; nj < 4; ++nj)
                acc[mi][nj] = __builtin_amdgcn_mfma_f32_16x16x32_bf16(
                    a[mi], b[nj], acc[mi][nj], 0, 0, 0);

        __builtin_amdgcn_sched_barrier(0);
        __builtin_amdgcn_s_barrier();
    }

    float bv[4];
    #pragma unroll
    for (int nj = 0; nj < 4; ++nj)
        bv[nj] = bias[col0 + wc * 64 + nj * 16 + l15];

    #pragma unroll
    for (int mi = 0; mi < 4; ++mi) {
        #pragma unroll
        for (int r = 0; r < 4; ++r) {
            const int row = row0 + wr * 64 + mi * 16 + l4 * 4 + r;
            #pragma unroll
            for (int nj = 0; nj < 4; ++nj) {
                const int col = col0 + wc * 64 + nj * 16 + l15;
                const float v = acc[mi][nj][r] + bv[nj];
                if (BF16OUT)
                    ((unsigned short*)Cout)[(size_t)row * N + col] = f2bf(v);
                else
                    ((float*)Cout)[(size_t)row * N + col] = v;
            }
        }
    }
}

// ---------------------------------------------------------------------------
// Flash attention v5 (R10-R13 version, verbatim — best measured, KVBLK=128).
// ---------------------------------------------------------------------------
__global__ __launch_bounds__(256, 2) void attn_mfma5_kernel(
    const unsigned short* __restrict__ qkv,   // roped+scaled qkv, bf16
    const unsigned short* __restrict__ vt,    // V^T global [(b*H+h)*64+d][T]
    unsigned short* __restrict__ out)         // [B*T][C] bf16
{
    __shared__ unsigned short Ks[2][128 * 64];   // [j][d], swizzled
    __shared__ unsigned short Vs[2][64 * 128];   // [d][j], swizzled

    const int idx = blockIdx.x;
    const int bh  = idx & 63;                 // b*16 + h
    const int qp  = idx >> 6;                 // 0..7
    const int b   = bh >> 4;
    const int h   = bh & 15;
    const int qtA = qp;
    const int qtB = 15 - qp;

    const int tid  = threadIdx.x;
    const int lane = tid & 63;
    const int w    = tid >> 6;
    const int l31  = lane & 31;
    const int hi   = lane >> 5;

    const int qwA = qtA * 128 + w * 32;
    const int qgA = qwA + l31;
    const int qwB = qtB * 128 + w * 32;
    const int qgB = qwB + l31;

    bf16x8 aqA[4], aqB[4];
    {
        const unsigned short* qpA = &qkv[(size_t)(b * T_ + qgA) * QKV_N + h * HS + hi * 8];
        const unsigned short* qpB = &qkv[(size_t)(b * T_ + qgB) * QKV_N + h * HS + hi * 8];
        #pragma unroll
        for (int kc = 0; kc < 4; ++kc) {
            aqA[kc] = *reinterpret_cast<const bf16x8*>(qpA + kc * 16);
            aqB[kc] = *reinterpret_cast<const bf16x8*>(qpB + kc * 16);
        }
    }

    f32x16 accA0 = {}, accA1 = {}, accB0 = {}, accB1 = {};
    float mA = -INFINITY, lA = 0.f, mB = -INFINITY, lB = 0.f;

    auto stageKV = [&](int buf, int it) {
        #pragma unroll
        for (int n = 0; n < 4; ++n) {
            const int r  = n * 32 + (tid >> 3);
            const int sk = ((tid & 7) ^ (r & 7)) * 8;
            gload16(&qkv[(size_t)(b * T_ + it * 128 + r) * QKV_N + C_ + h * HS + sk],
                    &Ks[buf][(n * 256 + tid) * 8]);
        }
        #pragma unroll
        for (int n = 0; n < 4; ++n) {
            const int d  = n * 16 + (tid >> 4);
            const int sv = ((tid & 15) ^ (d & 7)) * 8;
            gload16(&vt[((size_t)(bh * HS + d)) * T_ + it * 128 + sv],
                    &Vs[buf][(n * 256 + tid) * 8]);
        }
    };

    auto process = [&](const unsigned short* Kb, const unsigned short* Vb,
                       const bf16x8* aq, f32x16& a0, f32x16& a1,
                       float& mval, float& lval, int qw, int qg, int kbase) {
        f32x16 s[4] = {};
        __builtin_amdgcn_s_setprio(1);
        #pragma unroll
        for (int kc = 0; kc < 4; ++kc) {
            const int bo = kc * 32 + hi * 16;
            #pragma unroll
            for (int g = 0; g < 4; ++g) {
                const int rj = g * 32 + l31;
                const bf16x8 ak = *reinterpret_cast<const bf16x8*>(
                    &Kb[rj * 64 + ((bo ^ ((rj & 7) << 4)) >> 1)]);
                s[g] = __builtin_amdgcn_mfma_f32_32x32x16_bf16(ak, aq[kc], s[g], 0, 0, 0);
            }
        }
        __builtin_amdgcn_s_setprio(0);

        if (kbase + 127 > qw) {
            #pragma unroll
            for (int g = 0; g < 4; ++g) {
                #pragma unroll
                for (int r = 0; r < 16; ++r) {
                    const int j0 = kbase + g * 32 + (r & 3) + 8 * (r >> 2) + 4 * hi;
                    if (j0 > qg) s[g][r] = -INFINITY;
                }
            }
        }

        float tg[4];
        #pragma unroll
        for (int g = 0; g < 4; ++g) {
            const float v0 = FMAX3(s[g][0],  s[g][1],  s[g][2]);
            const float v1 = FMAX3(s[g][3],  s[g][4],  s[g][5]);
            const float v2 = FMAX3(s[g][6],  s[g][7],  s[g][8]);
            const float v3 = FMAX3(s[g][9],  s[g][10], s[g][11]);
            const float v4 = FMAX3(s[g][12], s[g][13], s[g][14]);
            tg[g] = fmaxf(FMAX3(v0, v1, v2), FMAX3(v3, v4, s[g][15]));
        }
        float tm = fmaxf(fmaxf(tg[0], tg[1]), fmaxf(tg[2], tg[3]));
        tm = fmaxf(tm, __shfl_xor(tm, 32));

        const bool upd = (tm > mval + 8.f);
        if (__ballot(upd)) {
            const float nm = upd ? tm : mval;
            const float sf = EXP2(mval - nm);
            lval *= sf;
            #pragma unroll
            for (int r = 0; r < 16; ++r) { a0[r] *= sf; a1[r] *= sf; }
            mval = nm;
        }

        float rs0 = 0.f, rs1 = 0.f, rs2 = 0.f, rs3 = 0.f;
        #pragma unroll
        for (int r = 0; r < 16; ++r) {
            s[0][r] = EXP2(s[0][r] - mval); rs0 += s[0][r];
            s[1][r] = EXP2(s[1][r] - mval); rs1 += s[1][r];
            s[2][r] = EXP2(s[2][r] - mval); rs2 += s[2][r];
            s[3][r] = EXP2(s[3][r] - mval); rs3 += s[3][r];
        }
        float rs = (rs0 + rs1) + (rs2 + rs3);
        rs += __shfl_xor(rs, 32);
        lval += rs;

        #pragma unroll
        for (int g2 = 0; g2 < 2; ++g2) {
            #pragma unroll
            for (int jt = 0; jt < 2; ++jt) {
                const int g = g2 * 2 + jt;
                #pragma unroll
                for (int c = 0; c < 2; ++c) {
                    const int e = c * 8;
                    const unsigned pa = cvtpk_bf16(s[g][e + 0], s[g][e + 1]);
                    const unsigned pb = cvtpk_bf16(s[g][e + 2], s[g][e + 3]);
                    const unsigned pc = cvtpk_bf16(s[g][e + 4], s[g][e + 5]);
                    const unsigned pd = cvtpk_bf16(s[g][e + 6], s[g][e + 7]);
                    int4 bw;
#if __has_builtin(__builtin_amdgcn_permlane32_swap)
                    const u32x2 rx = __builtin_amdgcn_permlane32_swap(pa, pc, false, false);
                    const u32x2 ry = __builtin_amdgcn_permlane32_swap(pb, pd, false, false);
                    bw.x = (int)rx[0]; bw.y = (int)ry[0];
                    bw.z = (int)rx[1]; bw.w = (int)ry[1];
#else
                    const unsigned pas = (unsigned)__shfl_xor((int)pa, 32);
                    const unsigned pbs = (unsigned)__shfl_xor((int)pb, 32);
                    const unsigned pcs = (unsigned)__shfl_xor((int)pc, 32);
                    const unsigned pds = (unsigned)__shfl_xor((int)pd, 32);
                    bw.x = (int)(hi ? pcs : pa);
                    bw.y = (int)(hi ? pds : pb);
                    bw.z = (int)(hi ? pc  : pas);
                    bw.w = (int)(hi ? pd  : pbs);
#endif
                    const bf16x8 bfrag = __builtin_bit_cast(bf16x8, bw);

                    const int lslot = g2 * 8 + (jt * 2 + c) * 2 + hi;
                    const int d0 = l31;
                    const bf16x8 av0 = *reinterpret_cast<const bf16x8*>(
                        &Vb[d0 * 128 + (lslot ^ (d0 & 7)) * 8]);
                    const int d1 = 32 + l31;
                    const bf16x8 av1 = *reinterpret_cast<const bf16x8*>(
                        &Vb[d1 * 128 + (lslot ^ (d1 & 7)) * 8]);
                    __builtin_amdgcn_s_setprio(1);
                    a0 = __builtin_amdgcn_mfma_f32_32x32x16_bf16(av0, bfrag, a0, 0, 0, 0);
                    a1 = __builtin_amdgcn_mfma_f32_32x32x16_bf16(av1, bfrag, a1, 0, 0, 0);
                    __builtin_amdgcn_s_setprio(0);
                }
            }
        }
    };

    const int nIter = qtB + 1;
    stageKV(0, 0);
    for (int it = 0; it < nIter; ++it) {
        const int cur = it & 1;
        __builtin_amdgcn_sched_barrier(0);
        if (it + 1 < nIter) {
            stageKV(cur ^ 1, it + 1);
            WAIT_VMCNT_8();
        } else {
            WAIT_VMCNT_0();
        }
        __builtin_amdgcn_s_barrier();
        __builtin_amdgcn_sched_barrier(0);

        const unsigned short* Kb = &Ks[cur][0];
        const unsigned short* Vb = &Vs[cur][0];
        const int kbase = it * 128;
        if (kbase <= qwA + 31)
            process(Kb, Vb, aqA, accA0, accA1, mA, lA, qwA, qgA, kbase);
        if (kbase <= qwB + 31)
            process(Kb, Vb, aqB, accB0, accB1, mB, lB, qwB, qgB, kbase);
        __builtin_amdgcn_sched_barrier(0);
        __builtin_amdgcn_s_barrier();
    }

    {
        const float inv = 1.0f / lA;
        unsigned short* orow = &out[(size_t)(b * T_ + qgA) * C_ + h * HS];
        #pragma unroll
        for (int g = 0; g < 4; ++g) {
            uint2 wv;
            wv.x = cvtpk_bf16(accA0[4 * g + 0] * inv, accA0[4 * g + 1] * inv);
            wv.y = cvtpk_bf16(accA0[4 * g + 2] * inv, accA0[4 * g + 3] * inv);
            *reinterpret_cast<uint2*>(&orow[8 * g + 4 * hi]) = wv;
            uint2 wv1;
            wv1.x = cvtpk_bf16(accA1[4 * g + 0] * inv, accA1[4 * g + 1] * inv);
            wv1.y = cvtpk_bf16(accA1[4 * g + 2] * inv, accA1[4 * g + 3] * inv);
            *reinterpret_cast<uint2*>(&orow[32 + 8 * g + 4 * hi]) = wv1;
        }
    }
    {
        const float inv = 1.0f / lB;
        unsigned short* orow = &out[(size_t)(b * T_ + qgB) * C_ + h * HS];
        #pragma unroll
        for (int g = 0; g < 4; ++g) {
            uint2 wv;
            wv.x = cvtpk_bf16(accB0[4 * g + 0] * inv, accB0[4 * g + 1] * inv);
            wv.y = cvtpk_bf16(accB0[4 * g + 2] * inv, accB0[4 * g + 3] * inv);
            *reinterpret_cast<uint2*>(&orow[8 * g + 4 * hi]) = wv;
            uint2 wv1;
            wv1.x = cvtpk_bf16(accB1[4 * g + 0] * inv, accB1[4 * g + 1] * inv);
            wv1.y = cvtpk_bf16(accB1[4 * g + 2] * inv, accB1[4 * g + 3] * inv);
            *reinterpret_cast<uint2*>(&orow[32 + 8 * g + 4 * hi]) = wv1;
        }
    }
}

// ---------------------------------------------------------------------------
extern "C" void kernel_launch(void* const* d_in, const int* in_sizes, int n_in,
                              void* d_out, int out_size, void* d_ws, size_t ws_size,
                              hipStream_t stream)
{
    const float* x    = (const float*)d_in[0];   // [B,T,C]
    const float* Wqkv = (const float*)d_in[1];   // [C,3C]
    const float* bqkv = (const float*)d_in[2];   // [3C]
    const float* Wout = (const float*)d_in[3];   // [C,C]
    const float* bout = (const float*)d_in[4];   // [C]
    float* out = (float*)d_out;                  // [B,T,C] fp32

    char* ws = (char*)d_ws;
    unsigned short* qkvb  = (unsigned short*)ws;                       // 50,331,648
    unsigned short* xb    = (unsigned short*)(ws + 50331648);          // 16,777,216
    unsigned short* attnb = (unsigned short*)(ws + 67108864);          // 16,777,216
    unsigned short* vt_g  = (unsigned short*)(ws + 83886080);          // 16,777,216
    unsigned short* Wqkvt = (unsigned short*)(ws + 100663296);         //  6,291,456
    unsigned short* Woutt = (unsigned short*)(ws + 106954752);         //  2,097,152
    float2* tab           = (float2*)(ws + 109051904);                 //    524,288

    // 1) fused prep: x cast + rope table + both weight transposes
    prep2_kernel<<<8448, 256, 0, stream>>>(x, xb, tab, Wqkv, Wout, Wqkvt, Woutt);

    // 2) QKV projection: 8-phase 256x256 (best measured for this shape)
    //    grid = 32*12 = 384 blocks
    gemm_8ph_kernel<QKV_N, C_, true, true, true>
        <<<(M_ / 256) * (QKV_N / 256), 512, 0, stream>>>(
        xb, Wqkvt, bqkv, tab, qkvb, vt_g, QKV_N / 256, M_ / 256);

    // 3) attention -> attnb [B,T,C] bf16 (KVBLK=128, 2 blocks/CU — best)
    attn_mfma5_kernel<<<B_ * H_ * (T_ / 256), 256, 0, stream>>>(qkvb, vt_g, attnb);

    // 4) output projection: 2-phase 128x128 (512 blocks, 4/CU)
    gemm_2ph_kernel<C_, C_, false>
        <<<(M_ / 128) * (C_ / 128), 256, 0, stream>>>(
        attnb, Woutt, bout, out, C_ / 128, M_ / 128);
}

// Round 19
// 166.670 us; speedup vs baseline: 1.4200x; 1.0011x over previous
//
#include <hip/hip_runtime.h>
#include <math.h>

// Problem constants (B=4, T=2048, C=1024, H=16, hs=64)
#define B_   4
#define T_   2048
#define C_   1024
#define H_   16
#define HS   64
#define HALF 32
#define QKV_N (3 * C_)      // 3072
#define M_    (B_ * T_)     // 8192

using bf16x8 = __attribute__((ext_vector_type(8))) short;
using f32x4  = __attribute__((ext_vector_type(4))) float;
using f32x16 = __attribute__((ext_vector_type(16))) float;
using u16x4  = __attribute__((ext_vector_type(4))) unsigned short;
using u32x2  = __attribute__((ext_vector_type(2))) unsigned int;

__device__ __forceinline__ unsigned short f2bf(float f) {
    unsigned u = __builtin_bit_cast(unsigned, f);
    u = (u + 0x7FFFu + ((u >> 16) & 1u)) >> 16;
    return (unsigned short)u;
}
__device__ __forceinline__ float bf2f(unsigned short b) {
    return __builtin_bit_cast(float, (unsigned)b << 16);
}
__device__ __forceinline__ unsigned cvtpk_bf16(float lo, float hi_) {
    unsigned r;
    asm("v_cvt_pk_bf16_f32 %0, %1, %2" : "=v"(r) : "v"(lo), "v"(hi_));
    return r;
}
__device__ __forceinline__ void gload16(const void* g, void* l) {
    __builtin_amdgcn_global_load_lds(
        (const __attribute__((address_space(1))) unsigned int*)g,
        (__attribute__((address_space(3))) unsigned int*)l, 16, 0, 0);
}
#define WAIT_VMCNT_8() asm volatile("s_waitcnt vmcnt(8)" ::: "memory")
#define WAIT_VMCNT_4() asm volatile("s_waitcnt vmcnt(4)" ::: "memory")
#define WAIT_VMCNT_0() asm volatile("s_waitcnt vmcnt(0)" ::: "memory")
#define WAIT_LGKM_0()  asm volatile("s_waitcnt lgkmcnt(0)" ::: "memory")

#if __has_builtin(__builtin_amdgcn_exp2f)
#define EXP2(x) __builtin_amdgcn_exp2f(x)
#else
#define EXP2(x) exp2f(x)
#endif
#define FMAX3(a, b, c) fmaxf(fmaxf((a), (b)), (c))

#define QSCALE 0.18033688011112042f   // 0.125 * log2(e), folded into Q

// ---------------------------------------------------------------------------
// prep2: blocks [0,4096): fp32->bf16 cast of x
//        blocks [4096,4352): RoPE sin/cos table
//        blocks [4352,7424): Wqkv transpose+cast
//        blocks [7424,8448): Wout transpose+cast
// ---------------------------------------------------------------------------
__global__ __launch_bounds__(256) void prep2_kernel(
    const float* __restrict__ x, unsigned short* __restrict__ xb,
    float2* __restrict__ tab,
    const float* __restrict__ Wqkv, const float* __restrict__ Wout,
    unsigned short* __restrict__ Wqkvt, unsigned short* __restrict__ Woutt)
{
    __shared__ float tile[32][33];
    const int bid = blockIdx.x;
    if (bid < 4096) {
        const size_t i = ((size_t)bid * 256 + threadIdx.x) * 8;
        const float4 a = *reinterpret_cast<const float4*>(&x[i]);
        const float4 b = *reinterpret_cast<const float4*>(&x[i + 4]);
        bf16x8 v;
        v[0] = f2bf(a.x); v[1] = f2bf(a.y); v[2] = f2bf(a.z); v[3] = f2bf(a.w);
        v[4] = f2bf(b.x); v[5] = f2bf(b.y); v[6] = f2bf(b.z); v[7] = f2bf(b.w);
        *reinterpret_cast<bf16x8*>(&xb[i]) = v;
        return;
    }
    if (bid < 4352) {
        const int idx = (bid - 4096) * 256 + threadIdx.x;   // 0 .. T_*HALF-1
        const int t = idx / HALF;
        const int i = idx % HALF;
        const float theta = powf(10000.0f, -(float)i / (float)HALF);
        const float ang = (float)t * theta;
        float sn, cs;
        sincosf(ang, &sn, &cs);
        tab[idx] = make_float2(sn, cs);
        return;
    }
    const float* W;
    unsigned short* Wt;
    int N, k0, n0;
    if (bid < 7424) {
        const int r0 = bid - 4352;
        W = Wqkv; Wt = Wqkvt; N = QKV_N;
        n0 = (r0 % 96) * 32; k0 = (r0 / 96) * 32;
    } else {
        const int r0 = bid - 7424;
        W = Wout; Wt = Woutt; N = C_;
        n0 = (r0 % 32) * 32; k0 = (r0 / 32) * 32;
    }
    const int K = C_;
    const int r = threadIdx.x / 32;
    const int c = threadIdx.x % 32;
    #pragma unroll
    for (int it = 0; it < 4; ++it)
        tile[r + it * 8][c] = W[(size_t)(k0 + r + it * 8) * N + n0 + c];
    __syncthreads();
    #pragma unroll
    for (int it = 0; it < 4; ++it)
        Wt[(size_t)(n0 + r + it * 8) * K + k0 + c] = f2bf(tile[c][r + it * 8]);
}

// ---------------------------------------------------------------------------
// 8-phase bf16 MFMA GEMM (QKV). BM=BN=256, BK=64, 512 threads = 8 waves,
// per-wave 128x64 (acc[8][4]). Counted vmcnt(4), granule-XOR swizzle,
// XCD-region map, fused RoPE + Q-prescale + V^T epilogue.
// ---------------------------------------------------------------------------
template <int N, int K, bool BF16OUT, bool ROPE, bool VSPLIT>
__global__ __launch_bounds__(512, 1) void gemm_8ph_kernel(
    const unsigned short* __restrict__ A, const unsigned short* __restrict__ Bt,
    const float* __restrict__ bias, const float2* __restrict__ tab,
    void* __restrict__ Cout, unsigned short* __restrict__ vt, int nbx, int nby)
{
    __shared__ unsigned short As0[2][128 * 64];
    __shared__ unsigned short As1[2][128 * 64];
    __shared__ unsigned short Bs0[2][128 * 64];
    __shared__ unsigned short Bs1[2][128 * 64];

    const int tid  = threadIdx.x;
    const int lane = tid & 63;
    const int wave = tid >> 6;        // 0..7
    const int wr   = wave >> 2;       // 0..1 : M half (128 rows)
    const int wc   = wave & 3;        // 0..3 : N quarter (64 cols)
    const int l15  = lane & 15;
    const int l4   = lane >> 4;

    const int bid  = blockIdx.x;
    const int xcd  = bid & 7;
    const int w    = bid >> 3;
    const int cpr  = nbx >> 1;
    const int rpr  = nby >> 2;
    const int by   = ((xcd >> 1) * rpr) + (w / cpr);
    const int bx   = ((xcd & 1) * cpr) + (w % cpr);
    const int row0 = by * 256;
    const int col0 = bx * 256;

    const int lr0 = tid >> 3,          sl0 = tid & 7;
    const int lr1 = (tid + 512) >> 3,  sl1 = (tid + 512) & 7;
    const int kc0 = (sl0 ^ (lr0 & 7)) * 8;
    const int kc1 = (sl1 ^ (lr1 & 7)) * 8;
    const int dA0 = tid * 8;
    const int dA1 = (tid + 512) * 8;
    const unsigned short* apS0 = &A[(size_t)(row0 + (lr0 >> 6) * 128 + (lr0 & 63)) * K + kc0];
    const unsigned short* apS1 = &A[(size_t)(row0 + (lr1 >> 6) * 128 + (lr1 & 63)) * K + kc1];
    const unsigned short* bpS0 = &Bt[(size_t)(col0 + (lr0 >> 5) * 64 + (lr0 & 31)) * K + kc0];
    const unsigned short* bpS1 = &Bt[(size_t)(col0 + (lr1 >> 5) * 64 + (lr1 & 31)) * K + kc1];

    auto stA0 = [&](int buf, int t) {
        gload16(apS0 + t * 64,            &As0[buf][dA0]);
        gload16(apS1 + t * 64,            &As0[buf][dA1]);
    };
    auto stA1 = [&](int buf, int t) {
        gload16(apS0 + t * 64 + 64 * K,   &As1[buf][dA0]);
        gload16(apS1 + t * 64 + 64 * K,   &As1[buf][dA1]);
    };
    auto stB0 = [&](int buf, int t) {
        gload16(bpS0 + t * 64,            &Bs0[buf][dA0]);
        gload16(bpS1 + t * 64,            &Bs0[buf][dA1]);
    };
    auto stB1 = [&](int buf, int t) {
        gload16(bpS0 + t * 64 + 32 * K,   &Bs1[buf][dA0]);
        gload16(bpS1 + t * 64 + 32 * K,   &Bs1[buf][dA1]);
    };

    int aoff[2][4], boff[2][2];
    #pragma unroll
    for (int kk = 0; kk < 2; ++kk) {
        #pragma unroll
        for (int mi = 0; mi < 4; ++mi) {
            const int lr = wr * 64 + mi * 16 + l15;
            aoff[kk][mi] = lr * 64 + (((kk * 4 + l4) ^ (lr & 7)) * 8);
        }
        #pragma unroll
        for (int nj = 0; nj < 2; ++nj) {
            const int lr = wc * 32 + nj * 16 + l15;
            boff[kk][nj] = lr * 64 + (((kk * 4 + l4) ^ (lr & 7)) * 8);
        }
    }

    f32x4 acc[8][4] = {};
    constexpr int nt = K / 64;

    stA0(0, 0); stB0(0, 0); stB1(0, 0); stA1(0, 0);
    WAIT_VMCNT_4();
    __builtin_amdgcn_s_barrier();

    bf16x8 a[2][4], b01[2][2], b23[2][2];

    for (int t = 0; t < nt; ++t) {
        const int cur = t & 1;
        const int nxt = cur ^ 1;
        const int tn  = (t + 1 < nt) ? t + 1 : 0;

        // phase 1: read A0+B0; stage A0(t+1); MFMA q(0,0)
        #pragma unroll
        for (int kk = 0; kk < 2; ++kk) {
            #pragma unroll
            for (int mi = 0; mi < 4; ++mi)
                a[kk][mi] = *reinterpret_cast<const bf16x8*>(&As0[cur][aoff[kk][mi]]);
            #pragma unroll
            for (int nj = 0; nj < 2; ++nj)
                b01[kk][nj] = *reinterpret_cast<const bf16x8*>(&Bs0[cur][boff[kk][nj]]);
        }
        stA0(nxt, tn);
        WAIT_VMCNT_4();
        __builtin_amdgcn_s_barrier();
        WAIT_LGKM_0();
        __builtin_amdgcn_sched_barrier(0);
        __builtin_amdgcn_s_setprio(1);
        #pragma unroll
        for (int kk = 0; kk < 2; ++kk)
            #pragma unroll
            for (int mi = 0; mi < 4; ++mi)
                #pragma unroll
                for (int nj = 0; nj < 2; ++nj)
                    acc[mi][nj] = __builtin_amdgcn_mfma_f32_16x16x32_bf16(
                        a[kk][mi], b01[kk][nj], acc[mi][nj], 0, 0, 0);
        __builtin_amdgcn_s_setprio(0);
        __builtin_amdgcn_sched_barrier(0);
        __builtin_amdgcn_s_barrier();

        // phase 2: read B1; stage B0(t+1); MFMA q(0,1)
        #pragma unroll
        for (int kk = 0; kk < 2; ++kk)
            #pragma unroll
            for (int nj = 0; nj < 2; ++nj)
                b23[kk][nj] = *reinterpret_cast<const bf16x8*>(&Bs1[cur][boff[kk][nj]]);
        stB0(nxt, tn);
        WAIT_VMCNT_4();
        __builtin_amdgcn_s_barrier();
        WAIT_LGKM_0();
        __builtin_amdgcn_sched_barrier(0);
        __builtin_amdgcn_s_setprio(1);
        #pragma unroll
        for (int kk = 0; kk < 2; ++kk)
            #pragma unroll
            for (int mi = 0; mi < 4; ++mi)
                #pragma unroll
                for (int nj = 0; nj < 2; ++nj)
                    acc[mi][2 + nj] = __builtin_amdgcn_mfma_f32_16x16x32_bf16(
                        a[kk][mi], b23[kk][nj], acc[mi][2 + nj], 0, 0, 0);
        __builtin_amdgcn_s_setprio(0);
        __builtin_amdgcn_sched_barrier(0);
        __builtin_amdgcn_s_barrier();

        // phase 3: read A1; stage B1(t+1); MFMA q(1,0)
        #pragma unroll
        for (int kk = 0; kk < 2; ++kk)
            #pragma unroll
            for (int mi = 0; mi < 4; ++mi)
                a[kk][mi] = *reinterpret_cast<const bf16x8*>(&As1[cur][aoff[kk][mi]]);
        stB1(nxt, tn);
        WAIT_VMCNT_4();
        __builtin_amdgcn_s_barrier();
        WAIT_LGKM_0();
        __builtin_amdgcn_sched_barrier(0);
        __builtin_amdgcn_s_setprio(1);
        #pragma unroll
        for (int kk = 0; kk < 2; ++kk)
            #pragma unroll
            for (int mi = 0; mi < 4; ++mi)
                #pragma unroll
                for (int nj = 0; nj < 2; ++nj)
                    acc[4 + mi][nj] = __builtin_amdgcn_mfma_f32_16x16x32_bf16(
                        a[kk][mi], b01[kk][nj], acc[4 + mi][nj], 0, 0, 0);
        __builtin_amdgcn_s_setprio(0);
        __builtin_amdgcn_sched_barrier(0);
        __builtin_amdgcn_s_barrier();

        // phase 4: stage A1(t+1); MFMA q(1,1)
        stA1(nxt, tn);
        WAIT_VMCNT_4();
        __builtin_amdgcn_s_barrier();
        __builtin_amdgcn_sched_barrier(0);
        __builtin_amdgcn_s_setprio(1);
        #pragma unroll
        for (int kk = 0; kk < 2; ++kk)
            #pragma unroll
            for (int mi = 0; mi < 4; ++mi)
                #pragma unroll
                for (int nj = 0; nj < 2; ++nj)
                    acc[4 + mi][2 + nj] = __builtin_amdgcn_mfma_f32_16x16x32_bf16(
                        a[kk][mi], b23[kk][nj], acc[4 + mi][2 + nj], 0, 0, 0);
        __builtin_amdgcn_s_setprio(0);
        __builtin_amdgcn_sched_barrier(0);
        __builtin_amdgcn_s_barrier();
    }
    WAIT_VMCNT_0();

    float bv[4];
    #pragma unroll
    for (int nf = 0; nf < 4; ++nf)
        bv[nf] = bias[col0 + wc * 64 + nf * 16 + l15];

    if (VSPLIT && col0 >= 2 * C_) {
        #pragma unroll
        for (int mf = 0; mf < 8; ++mf) {
            const int rowb = row0 + wr * 128 + mf * 16 + l4 * 4;
            const int b  = rowb >> 11;
            const int t0 = rowb & (T_ - 1);
            #pragma unroll
            for (int nf = 0; nf < 4; ++nf) {
                const int cv = col0 - 2 * C_ + wc * 64 + nf * 16 + l15;
                u16x4 pack;
                #pragma unroll
                for (int r = 0; r < 4; ++r)
                    pack[r] = f2bf(acc[mf][nf][r] + bv[nf]);
                *reinterpret_cast<u16x4*>(
                    &vt[((size_t)(b * H_ * HS + cv)) * T_ + t0]) = pack;
            }
        }
        return;
    }

    const bool doRope = ROPE && (col0 < 2 * C_);
    const bool doScaleQ = ROPE && (col0 < C_);

    #pragma unroll
    for (int mf = 0; mf < 8; ++mf) {
        #pragma unroll
        for (int r = 0; r < 4; ++r) {
            const int row = row0 + wr * 128 + mf * 16 + l4 * 4 + r;
            const int t   = row & (T_ - 1);
            #pragma unroll
            for (int nf = 0; nf < 4; ++nf) {
                const int col = col0 + wc * 64 + nf * 16 + l15;
                float v = acc[mf][nf][r] + bv[nf];
                if (doRope) {
                    const float partner = __shfl_xor(v, 1);
                    const float2 sc = tab[t * HALF + ((col & 63) >> 1)];
                    v = v * sc.y + ((col & 1) ? partner : -partner) * sc.x;
                }
                if (doScaleQ) v *= QSCALE;
                if (BF16OUT)
                    ((unsigned short*)Cout)[(size_t)row * N + col] = f2bf(v);
                else
                    ((float*)Cout)[(size_t)row * N + col] = v;
            }
        }
    }
}

// ---------------------------------------------------------------------------
// 2-phase 128x128 bf16 MFMA GEMM (out-projection, 512 blocks, 4/CU).
// ---------------------------------------------------------------------------
template <int N, int K, bool BF16OUT>
__global__ __launch_bounds__(256, 4) void gemm_2ph_kernel(
    const unsigned short* __restrict__ A, const unsigned short* __restrict__ Bt,
    const float* __restrict__ bias, void* __restrict__ Cout, int nbx, int nby)
{
    __shared__ unsigned short As[2][128 * 32];
    __shared__ unsigned short Bs[2][128 * 32];

    const int tid  = threadIdx.x;
    const int lane = tid & 63;
    const int wave = tid >> 6;
    const int wr   = wave >> 1;
    const int wc   = wave & 1;
    const int l15  = lane & 15;
    const int l4   = lane >> 4;

    const int bid  = blockIdx.x;
    const int xcd  = bid & 7;
    const int w    = bid >> 3;
    const int cpr  = nbx >> 1;
    const int rpr  = nby >> 2;
    const int by   = ((xcd >> 1) * rpr) + (w / cpr);
    const int bx   = ((xcd & 1) * cpr) + (w % cpr);
    const int row0 = by * 128;
    const int col0 = bx * 128;

    f32x4 acc[4][4] = {};

    const int ar  = tid >> 2;
    const int sl  = tid & 3;
    const int swz = (sl ^ ((ar >> 1) & 3)) * 8;
    const unsigned short* ap = &A[(size_t)(row0 + ar) * K + swz];
    const unsigned short* bp = &Bt[(size_t)(col0 + ar) * K + swz];

    auto stage = [&](int buf, int t) {
        const unsigned short* a0 = ap + t * 32;
        const unsigned short* b0 = bp + t * 32;
        gload16(a0,          &As[buf][tid * 8]);
        gload16(a0 + 64 * K, &As[buf][(tid + 256) * 8]);
        gload16(b0,          &Bs[buf][tid * 8]);
        gload16(b0 + 64 * K, &Bs[buf][(tid + 256) * 8]);
    };

    int aoff[4], boff[4];
    #pragma unroll
    for (int mi = 0; mi < 4; ++mi) {
        const int lr = wr * 64 + mi * 16 + l15;
        aoff[mi] = lr * 32 + ((l4 ^ ((lr >> 1) & 3)) * 8);
    }
    #pragma unroll
    for (int nj = 0; nj < 4; ++nj) {
        const int lr = wc * 64 + nj * 16 + l15;
        boff[nj] = lr * 32 + ((l4 ^ ((lr >> 1) & 3)) * 8);
    }

    constexpr int nt = K / 32;
    stage(0, 0);

    for (int t = 0; t < nt; ++t) {
        const int cur = t & 1;
        if (t + 1 < nt) {
            stage(cur ^ 1, t + 1);
            WAIT_VMCNT_4();
        } else {
            WAIT_VMCNT_0();
        }
        __builtin_amdgcn_s_barrier();
        __builtin_amdgcn_sched_barrier(0);

        bf16x8 a[4], b[4];
        #pragma unroll
        for (int mi = 0; mi < 4; ++mi)
            a[mi] = *reinterpret_cast<const bf16x8*>(&As[cur][aoff[mi]]);
        #pragma unroll
        for (int nj = 0; nj < 4; ++nj)
            b[nj] = *reinterpret_cast<const bf16x8*>(&Bs[cur][boff[nj]]);
        #pragma unroll
        for (int mi = 0; mi < 4; ++mi)
            #pragma unroll
            for (int nj = 0; nj < 4; ++nj)
                acc[mi][nj] = __builtin_amdgcn_mfma_f32_16x16x32_bf16(
                    a[mi], b[nj], acc[mi][nj], 0, 0, 0);

        __builtin_amdgcn_sched_barrier(0);
        __builtin_amdgcn_s_barrier();
    }

    float bv[4];
    #pragma unroll
    for (int nj = 0; nj < 4; ++nj)
        bv[nj] = bias[col0 + wc * 64 + nj * 16 + l15];

    #pragma unroll
    for (int mi = 0; mi < 4; ++mi) {
        #pragma unroll
        for (int r = 0; r < 4; ++r) {
            const int row = row0 + wr * 64 + mi * 16 + l4 * 4 + r;
            #pragma unroll
            for (int nj = 0; nj < 4; ++nj) {
                const int col = col0 + wc * 64 + nj * 16 + l15;
                const float v = acc[mi][nj][r] + bv[nj];
                if (BF16OUT)
                    ((unsigned short*)Cout)[(size_t)row * N + col] = f2bf(v);
                else
                    ((float*)Cout)[(size_t)row * N + col] = v;
            }
        }
    }
}

// ---------------------------------------------------------------------------
// Flash attention v5 (best measured, KVBLK=128, 2 blocks/CU).
// ---------------------------------------------------------------------------
__global__ __launch_bounds__(256, 2) void attn_mfma5_kernel(
    const unsigned short* __restrict__ qkv,   // roped+scaled qkv, bf16
    const unsigned short* __restrict__ vt,    // V^T global [(b*H+h)*64+d][T]
    unsigned short* __restrict__ out)         // [B*T][C] bf16
{
    __shared__ unsigned short Ks[2][128 * 64];   // [j][d], swizzled
    __shared__ unsigned short Vs[2][64 * 128];   // [d][j], swizzled

    const int idx = blockIdx.x;
    const int bh  = idx & 63;                 // b*16 + h
    const int qp  = idx >> 6;                 // 0..7
    const int b   = bh >> 4;
    const int h   = bh & 15;
    const int qtA = qp;
    const int qtB = 15 - qp;

    const int tid  = threadIdx.x;
    const int lane = tid & 63;
    const int w    = tid >> 6;
    const int l31  = lane & 31;
    const int hi   = lane >> 5;

    const int qwA = qtA * 128 + w * 32;
    const int qgA = qwA + l31;
    const int qwB = qtB * 128 + w * 32;
    const int qgB = qwB + l31;

    bf16x8 aqA[4], aqB[4];
    {
        const unsigned short* qpA = &qkv[(size_t)(b * T_ + qgA) * QKV_N + h * HS + hi * 8];
        const unsigned short* qpB = &qkv[(size_t)(b * T_ + qgB) * QKV_N + h * HS + hi * 8];
        #pragma unroll
        for (int kc = 0; kc < 4; ++kc) {
            aqA[kc] = *reinterpret_cast<const bf16x8*>(qpA + kc * 16);
            aqB[kc] = *reinterpret_cast<const bf16x8*>(qpB + kc * 16);
        }
    }

    f32x16 accA0 = {}, accA1 = {}, accB0 = {}, accB1 = {};
    float mA = -INFINITY, lA = 0.f, mB = -INFINITY, lB = 0.f;

    auto stageKV = [&](int buf, int it) {
        #pragma unroll
        for (int n = 0; n < 4; ++n) {
            const int r  = n * 32 + (tid >> 3);
            const int sk = ((tid & 7) ^ (r & 7)) * 8;
            gload16(&qkv[(size_t)(b * T_ + it * 128 + r) * QKV_N + C_ + h * HS + sk],
                    &Ks[buf][(n * 256 + tid) * 8]);
        }
        #pragma unroll
        for (int n = 0; n < 4; ++n) {
            const int d  = n * 16 + (tid >> 4);
            const int sv = ((tid & 15) ^ (d & 7)) * 8;
            gload16(&vt[((size_t)(bh * HS + d)) * T_ + it * 128 + sv],
                    &Vs[buf][(n * 256 + tid) * 8]);
        }
    };

    auto process = [&](const unsigned short* Kb, const unsigned short* Vb,
                       const bf16x8* aq, f32x16& a0, f32x16& a1,
                       float& mval, float& lval, int qw, int qg, int kbase) {
        f32x16 s[4] = {};
        __builtin_amdgcn_s_setprio(1);
        #pragma unroll
        for (int kc = 0; kc < 4; ++kc) {
            const int bo = kc * 32 + hi * 16;
            #pragma unroll
            for (int g = 0; g < 4; ++g) {
                const int rj = g * 32 + l31;
                const bf16x8 ak = *reinterpret_cast<const bf16x8*>(
                    &Kb[rj * 64 + ((bo ^ ((rj & 7) << 4)) >> 1)]);
                s[g] = __builtin_amdgcn_mfma_f32_32x32x16_bf16(ak, aq[kc], s[g], 0, 0, 0);
            }
        }
        __builtin_amdgcn_s_setprio(0);

        if (kbase + 127 > qw) {
            #pragma unroll
            for (int g = 0; g < 4; ++g) {
                #pragma unroll
                for (int r = 0; r < 16; ++r) {
                    const int j0 = kbase + g * 32 + (r & 3) + 8 * (r >> 2) + 4 * hi;
                    if (j0 > qg) s[g][r] = -INFINITY;
                }
            }
        }

        float tg[4];
        #pragma unroll
        for (int g = 0; g < 4; ++g) {
            const float v0 = FMAX3(s[g][0],  s[g][1],  s[g][2]);
            const float v1 = FMAX3(s[g][3],  s[g][4],  s[g][5]);
            const float v2 = FMAX3(s[g][6],  s[g][7],  s[g][8]);
            const float v3 = FMAX3(s[g][9],  s[g][10], s[g][11]);
            const float v4 = FMAX3(s[g][12], s[g][13], s[g][14]);
            tg[g] = fmaxf(FMAX3(v0, v1, v2), FMAX3(v3, v4, s[g][15]));
        }
        float tm = fmaxf(fmaxf(tg[0], tg[1]), fmaxf(tg[2], tg[3]));
        tm = fmaxf(tm, __shfl_xor(tm, 32));

        const bool upd = (tm > mval + 8.f);
        if (__ballot(upd)) {
            const float nm = upd ? tm : mval;
            const float sf = EXP2(mval - nm);
            lval *= sf;
            #pragma unroll
            for (int r = 0; r < 16; ++r) { a0[r] *= sf; a1[r] *= sf; }
            mval = nm;
        }

        float rs0 = 0.f, rs1 = 0.f, rs2 = 0.f, rs3 = 0.f;
        #pragma unroll
        for (int r = 0; r < 16; ++r) {
            s[0][r] = EXP2(s[0][r] - mval); rs0 += s[0][r];
            s[1][r] = EXP2(s[1][r] - mval); rs1 += s[1][r];
            s[2][r] = EXP2(s[2][r] - mval); rs2 += s[2][r];
            s[3][r] = EXP2(s[3][r] - mval); rs3 += s[3][r];
        }
        float rs = (rs0 + rs1) + (rs2 + rs3);
        rs += __shfl_xor(rs, 32);
        lval += rs;

        #pragma unroll
        for (int g2 = 0; g2 < 2; ++g2) {
            #pragma unroll
            for (int jt = 0; jt < 2; ++jt) {
                const int g = g2 * 2 + jt;
                #pragma unroll
                for (int c = 0; c < 2; ++c) {
                    const int e = c * 8;
                    const unsigned pa = cvtpk_bf16(s[g][e + 0], s[g][e + 1]);
                    const unsigned pb = cvtpk_bf16(s[g][e + 2], s[g][e + 3]);
                    const unsigned pc = cvtpk_bf16(s[g][e + 4], s[g][e + 5]);
                    const unsigned pd = cvtpk_bf16(s[g][e + 6], s[g][e + 7]);
                    int4 bw;
#if __has_builtin(__builtin_amdgcn_permlane32_swap)
                    const u32x2 rx = __builtin_amdgcn_permlane32_swap(pa, pc, false, false);
                    const u32x2 ry = __builtin_amdgcn_permlane32_swap(pb, pd, false, false);
                    bw.x = (int)rx[0]; bw.y = (int)ry[0];
                    bw.z = (int)rx[1]; bw.w = (int)ry[1];
#else
                    const unsigned pas = (unsigned)__shfl_xor((int)pa, 32);
                    const unsigned pbs = (unsigned)__shfl_xor((int)pb, 32);
                    const unsigned pcs = (unsigned)__shfl_xor((int)pc, 32);
                    const unsigned pds = (unsigned)__shfl_xor((int)pd, 32);
                    bw.x = (int)(hi ? pcs : pa);
                    bw.y = (int)(hi ? pds : pb);
                    bw.z = (int)(hi ? pc  : pas);
                    bw.w = (int)(hi ? pd  : pbs);
#endif
                    const bf16x8 bfrag = __builtin_bit_cast(bf16x8, bw);

                    const int lslot = g2 * 8 + (jt * 2 + c) * 2 + hi;
                    const int d0 = l31;
                    const bf16x8 av0 = *reinterpret_cast<const bf16x8*>(
                        &Vb[d0 * 128 + (lslot ^ (d0 & 7)) * 8]);
                    const int d1 = 32 + l31;
                    const bf16x8 av1 = *reinterpret_cast<const bf16x8*>(
                        &Vb[d1 * 128 + (lslot ^ (d1 & 7)) * 8]);
                    __builtin_amdgcn_s_setprio(1);
                    a0 = __builtin_amdgcn_mfma_f32_32x32x16_bf16(av0, bfrag, a0, 0, 0, 0);
                    a1 = __builtin_amdgcn_mfma_f32_32x32x16_bf16(av1, bfrag, a1, 0, 0, 0);
                    __builtin_amdgcn_s_setprio(0);
                }
            }
        }
    };

    const int nIter = qtB + 1;
    stageKV(0, 0);
    for (int it = 0; it < nIter; ++it) {
        const int cur = it & 1;
        __builtin_amdgcn_sched_barrier(0);
        if (it + 1 < nIter) {
            stageKV(cur ^ 1, it + 1);
            WAIT_VMCNT_8();
        } else {
            WAIT_VMCNT_0();
        }
        __builtin_amdgcn_s_barrier();
        __builtin_amdgcn_sched_barrier(0);

        const unsigned short* Kb = &Ks[cur][0];
        const unsigned short* Vb = &Vs[cur][0];
        const int kbase = it * 128;
        if (kbase <= qwA + 31)
            process(Kb, Vb, aqA, accA0, accA1, mA, lA, qwA, qgA, kbase);
        if (kbase <= qwB + 31)
            process(Kb, Vb, aqB, accB0, accB1, mB, lB, qwB, qgB, kbase);
        __builtin_amdgcn_sched_barrier(0);
        __builtin_amdgcn_s_barrier();
    }

    {
        const float inv = 1.0f / lA;
        unsigned short* orow = &out[(size_t)(b * T_ + qgA) * C_ + h * HS];
        #pragma unroll
        for (int g = 0; g < 4; ++g) {
            uint2 wv;
            wv.x = cvtpk_bf16(accA0[4 * g + 0] * inv, accA0[4 * g + 1] * inv);
            wv.y = cvtpk_bf16(accA0[4 * g + 2] * inv, accA0[4 * g + 3] * inv);
            *reinterpret_cast<uint2*>(&orow[8 * g + 4 * hi]) = wv;
            uint2 wv1;
            wv1.x = cvtpk_bf16(accA1[4 * g + 0] * inv, accA1[4 * g + 1] * inv);
            wv1.y = cvtpk_bf16(accA1[4 * g + 2] * inv, accA1[4 * g + 3] * inv);
            *reinterpret_cast<uint2*>(&orow[32 + 8 * g + 4 * hi]) = wv1;
        }
    }
    {
        const float inv = 1.0f / lB;
        unsigned short* orow = &out[(size_t)(b * T_ + qgB) * C_ + h * HS];
        #pragma unroll
        for (int g = 0; g < 4; ++g) {
            uint2 wv;
            wv.x = cvtpk_bf16(accB0[4 * g + 0] * inv, accB0[4 * g + 1] * inv);
            wv.y = cvtpk_bf16(accB0[4 * g + 2] * inv, accB0[4 * g + 3] * inv);
            *reinterpret_cast<uint2*>(&orow[8 * g + 4 * hi]) = wv;
            uint2 wv1;
            wv1.x = cvtpk_bf16(accB1[4 * g + 0] * inv, accB1[4 * g + 1] * inv);
            wv1.y = cvtpk_bf16(accB1[4 * g + 2] * inv, accB1[4 * g + 3] * inv);
            *reinterpret_cast<uint2*>(&orow[32 + 8 * g + 4 * hi]) = wv1;
        }
    }
}

// ---------------------------------------------------------------------------
extern "C" void kernel_launch(void* const* d_in, const int* in_sizes, int n_in,
                              void* d_out, int out_size, void* d_ws, size_t ws_size,
                              hipStream_t stream)
{
    const float* x    = (const float*)d_in[0];   // [B,T,C]
    const float* Wqkv = (const float*)d_in[1];   // [C,3C]
    const float* bqkv = (const float*)d_in[2];   // [3C]
    const float* Wout = (const float*)d_in[3];   // [C,C]
    const float* bout = (const float*)d_in[4];   // [C]
    float* out = (float*)d_out;                  // [B,T,C] fp32

    char* ws = (char*)d_ws;
    unsigned short* qkvb  = (unsigned short*)ws;                       // 50,331,648
    unsigned short* xb    = (unsigned short*)(ws + 50331648);          // 16,777,216
    unsigned short* attnb = (unsigned short*)(ws + 67108864);          // 16,777,216
    unsigned short* vt_g  = (unsigned short*)(ws + 83886080);          // 16,777,216
    unsigned short* Wqkvt = (unsigned short*)(ws + 100663296);         //  6,291,456
    unsigned short* Woutt = (unsigned short*)(ws + 106954752);         //  2,097,152
    float2* tab           = (float2*)(ws + 109051904);                 //    524,288

    // 1) fused prep: x cast + rope table + both weight transposes
    prep2_kernel<<<8448, 256, 0, stream>>>(x, xb, tab, Wqkv, Wout, Wqkvt, Woutt);

    // 2) QKV projection: 8-phase 256x256 (best measured for this shape)
    gemm_8ph_kernel<QKV_N, C_, true, true, true>
        <<<(M_ / 256) * (QKV_N / 256), 512, 0, stream>>>(
        xb, Wqkvt, bqkv, tab, qkvb, vt_g, QKV_N / 256, M_ / 256);

    // 3) attention -> attnb [B,T,C] bf16 (KVBLK=128, 2 blocks/CU — best)
    attn_mfma5_kernel<<<B_ * H_ * (T_ / 256), 256, 0, stream>>>(qkvb, vt_g, attnb);

    // 4) output projection: 2-phase 128x128 (512 blocks, 4/CU)
    gemm_2ph_kernel<C_, C_, false>
        <<<(M_ / 128) * (C_ / 128), 256, 0, stream>>>(
        attnb, Woutt, bout, out, C_ / 128, M_ / 128);
}